// Round 1
// baseline (285.630 us; speedup 1.0000x reference)
//
#include <hip/hip_runtime.h>
#include <hip/hip_bf16.h>
#include <stdint.h>

// Problem constants: B=2, M=8192, D=1024, H=16, hd=64, SEG=2048, DIL=8
// => S=4 segments, Kn=256 dilated keys/segment, nb=32 query blocks of 64.
// Dilated key rows are global rows ≡ 0 (mod 8).

typedef __attribute__((ext_vector_type(8))) short short8;
typedef __attribute__((ext_vector_type(4))) float f32x4;

#define DEVI static __device__ __forceinline__

DEVI unsigned short f2bf(float f) {
  union { float f; uint32_t u; } v; v.f = f;
  return (unsigned short)((v.u + 0x7FFFu + ((v.u >> 16) & 1u)) >> 16);
}

DEVI void gload_lds16(const void* g, void* l) {
  __builtin_amdgcn_global_load_lds((const __attribute__((address_space(1))) void*)g,
                                   (__attribute__((address_space(3))) void*)l,
                                   16, 0, 0);
}

// ---------------- f32 -> bf16 convert (weights only) ----------------
__global__ void cvt_kernel(const float* __restrict__ in, unsigned short* __restrict__ out, int n) {
  int i = (blockIdx.x * 256 + threadIdx.x) * 4;
  if (i >= n) return;
  float4 f = *(const float4*)(in + i);
  uint2 o;
  o.x = (uint32_t)f2bf(f.x) | ((uint32_t)f2bf(f.y) << 16);
  o.y = (uint32_t)f2bf(f.z) | ((uint32_t)f2bf(f.w) << 16);
  *(uint2*)(out + i) = o;
}

// ---------------- GEMM: C[m,n] = scale * sum_k A[m,k]*B[n,k] ----------------
// A: f32 (A_F32) or bf16; row m starts at A + m*a_row_stride elements.
// B: bf16 [N][K] row-major. C: f32 (OUT_F32) or bf16.
// 128x128 tile, BK=64, 4 waves (2x2 quadrants of 64x64), 16x16x32 bf16 MFMA.
// LDS tiles hold chunk-XOR-swizzled layout; global source chunk is pre-swizzled
// so global_load_lds (linear dest) produces the swizzled layout (rule #21).
template<bool A_F32, bool OUT_F32>
__global__ __launch_bounds__(256, 2) void gemm_bt(
    const void* __restrict__ Av, const unsigned short* __restrict__ B,
    void* __restrict__ Cv, float scale, long a_row_stride, int ldc, int K)
{
  __shared__ unsigned short smA[128 * 64];
  __shared__ unsigned short smB[128 * 64];
  const int tid = threadIdx.x;
  const int tm = blockIdx.x, tn = blockIdx.y;
  const int w = tid >> 6, lane = tid & 63;
  const int wr = (w >> 1) * 64, wc = (w & 1) * 64;
  const int lr = lane & 15, lq = lane >> 4;

  int se[4], srow[4], scol[4];
#pragma unroll
  for (int i = 0; i < 4; ++i) {
    int e = (i * 256 + tid) * 8;   // lds element offset of this thread's 16B slot
    int r = e >> 6;                // row 0..127
    int cc = (e >> 3) & 7;         // 16B chunk within row
    se[i] = e; srow[i] = r; scol[i] = (cc ^ (r & 7)) * 8;  // pre-swizzled source col
  }

  f32x4 acc[4][4] = {};

  for (int kt = 0; kt < K / 64; ++kt) {
    if (kt) __syncthreads();
    if (A_F32) {
      const float* Af = (const float*)Av;
#pragma unroll
      for (int i = 0; i < 4; ++i) {
        const float* src = Af + (long)(tm * 128 + srow[i]) * a_row_stride + kt * 64 + scol[i];
        float4 f0 = *(const float4*)src;
        float4 f1 = *(const float4*)(src + 4);
        short8 o;
        o[0]=(short)f2bf(f0.x); o[1]=(short)f2bf(f0.y); o[2]=(short)f2bf(f0.z); o[3]=(short)f2bf(f0.w);
        o[4]=(short)f2bf(f1.x); o[5]=(short)f2bf(f1.y); o[6]=(short)f2bf(f1.z); o[7]=(short)f2bf(f1.w);
        *(short8*)&smA[se[i]] = o;
      }
    } else {
      const unsigned short* Ab = (const unsigned short*)Av;
#pragma unroll
      for (int i = 0; i < 4; ++i)
        gload_lds16(Ab + (long)(tm * 128 + srow[i]) * a_row_stride + kt * 64 + scol[i], &smA[se[i]]);
    }
#pragma unroll
    for (int i = 0; i < 4; ++i)
      gload_lds16(B + (long)(tn * 128 + srow[i]) * K + kt * 64 + scol[i], &smB[se[i]]);
    __syncthreads();

#pragma unroll
    for (int kk = 0; kk < 2; ++kk) {
      int kc = kk * 4 + lq;
      short8 af[4], bfm[4];
#pragma unroll
      for (int i = 0; i < 4; ++i) {
        int row = wr + i * 16 + lr;
        af[i] = *(const short8*)&smA[row * 64 + ((kc ^ (row & 7)) * 8)];
      }
#pragma unroll
      for (int j = 0; j < 4; ++j) {
        int row = wc + j * 16 + lr;
        bfm[j] = *(const short8*)&smB[row * 64 + ((kc ^ (row & 7)) * 8)];
      }
#pragma unroll
      for (int i = 0; i < 4; ++i)
#pragma unroll
        for (int j = 0; j < 4; ++j)
          acc[i][j] = __builtin_amdgcn_mfma_f32_16x16x32_bf16(af[i], bfm[j], acc[i][j], 0, 0, 0);
    }
  }

#pragma unroll
  for (int i = 0; i < 4; ++i) {
    int rg0 = tm * 128 + wr + i * 16 + lq * 4;
#pragma unroll
    for (int j = 0; j < 4; ++j) {
      int cg = tn * 128 + wc + j * 16 + lr;
#pragma unroll
      for (int r = 0; r < 4; ++r) {
        float v = acc[i][j][r] * scale;
        long off = (long)(rg0 + r) * ldc + cg;
        if (OUT_F32) ((float*)Cv)[off] = v;
        else         ((unsigned short*)Cv)[off] = f2bf(v);
      }
    }
  }
}

// ---------------- segment-local dilated attention ----------------
// One block: 64 queries (one BLOCK_M) x 256 keys (two 128-key halves) for one (b,h,s).
// Normalization is per KEY column over the 64-query block (exactly per reference),
// so key-halves need no cross-half rescaling; num/den just accumulate.
__global__ __launch_bounds__(256, 2) void attn_kernel(
    const unsigned short* __restrict__ qb,    // [16384][1024] bf16, q*scale
    const unsigned short* __restrict__ kvb,   // [2048][2048] bf16: [k(1024) | v(1024)]
    unsigned short* __restrict__ attout)      // [16384][1024] bf16, col = h*64+d
{
  __shared__ unsigned short q_t[64 * 64];     // [p][d]   swizzled
  __shared__ unsigned short k_t[128 * 64];    // [j][d]   swizzled
  __shared__ unsigned short v_t[64 * 128];    // [d][j]   transposed, swizzled
  __shared__ unsigned short w_lds[64 * 128];  // [p][j]   swizzled
  __shared__ float den_part[4][64];

  const int bid = blockIdx.x;
  const int mb = bid & 31, s = (bid >> 5) & 3, h = (bid >> 7) & 15, b = bid >> 11;
  const int tid = threadIdx.x, w = tid >> 6, lane = tid & 63;
  const int lr = lane & 15, lq = lane >> 4;
  const long qrow0 = (long)b * 8192 + s * 2048 + mb * 64;
  const long kvrow0 = (long)b * 1024 + s * 256;
  const int hc = h * 64;

  den_part[tid >> 6][tid & 63] = 0.f;

#pragma unroll
  for (int st = 0; st < 2; ++st) {           // stage Q 64x64
    int row = st * 32 + (tid >> 3);
    int c8 = tid & 7;
    short8 d = *(const short8*)&qb[(qrow0 + row) * 1024 + hc + c8 * 8];
    *(short8*)&q_t[row * 64 + ((c8 ^ (row & 7)) * 8)] = d;
  }

  f32x4 acc_pv[4] = {};

  for (int half = 0; half < 2; ++half) {
    const long kr0 = kvrow0 + half * 128;
#pragma unroll
    for (int st = 0; st < 4; ++st) {         // stage K 128x64
      int j = st * 32 + (tid >> 3);
      int c8 = tid & 7;
      short8 d = *(const short8*)&kvb[(kr0 + j) * 2048 + hc + c8 * 8];
      *(short8*)&k_t[j * 64 + ((c8 ^ (j & 7)) * 8)] = d;
    }
#pragma unroll
    for (int st = 0; st < 4; ++st) {         // stage V transposed [d][j]
      int j = st * 32 + (tid >> 3);
      int c8 = tid & 7;
      short8 dv = *(const short8*)&kvb[(kr0 + j) * 2048 + 1024 + hc + c8 * 8];
#pragma unroll
      for (int e = 0; e < 8; ++e) {
        int dcol = c8 * 8 + e;
        v_t[dcol * 128 + (((j >> 3) ^ (dcol & 7)) * 8) + (j & 7)] = (unsigned short)(short)dv[e];
      }
    }
    __syncthreads();

    // QK^T: wave w owns score columns [w*32, w*32+32), all 64 query rows
    f32x4 acc_s[4][2] = {};
#pragma unroll
    for (int kk = 0; kk < 2; ++kk) {
      int kc = kk * 4 + lq;
      short8 aq[4], bk[2];
#pragma unroll
      for (int i = 0; i < 4; ++i) {
        int row = i * 16 + lr;
        aq[i] = *(const short8*)&q_t[row * 64 + ((kc ^ (row & 7)) * 8)];
      }
#pragma unroll
      for (int j = 0; j < 2; ++j) {
        int row = w * 32 + j * 16 + lr;
        bk[j] = *(const short8*)&k_t[row * 64 + ((kc ^ (row & 7)) * 8)];
      }
#pragma unroll
      for (int i = 0; i < 4; ++i)
#pragma unroll
        for (int j = 0; j < 2; ++j)
          acc_s[i][j] = __builtin_amdgcn_mfma_f32_16x16x32_bf16(aq[i], bk[j], acc_s[i][j], 0, 0, 0);
    }

    // per-key (column) max over 64 queries: in-lane over (i,r), cross-lane over lq
    float cmax[2];
#pragma unroll
    for (int j = 0; j < 2; ++j) {
      float m = -3.4e38f;
#pragma unroll
      for (int i = 0; i < 4; ++i)
#pragma unroll
        for (int r = 0; r < 4; ++r) m = fmaxf(m, acc_s[i][j][r]);
      m = fmaxf(m, __shfl_xor(m, 16));
      m = fmaxf(m, __shfl_xor(m, 32));
      cmax[j] = m;
    }

    // w = exp(s - cmax_col); write bf16 to w_lds; accumulate row sums (den)
#pragma unroll
    for (int i = 0; i < 4; ++i) {
#pragma unroll
      for (int r = 0; r < 4; ++r) {
        int prow = i * 16 + lq * 4 + r;
        float rs = 0.f;
#pragma unroll
        for (int j = 0; j < 2; ++j) {
          float wv = __expf(acc_s[i][j][r] - cmax[j]);
          rs += wv;
          int col = w * 32 + j * 16 + lr;
          w_lds[prow * 128 + (((col >> 3) ^ (prow & 7)) * 8) + (col & 7)] = f2bf(wv);
        }
        rs += __shfl_xor(rs, 1);
        rs += __shfl_xor(rs, 2);
        rs += __shfl_xor(rs, 4);
        rs += __shfl_xor(rs, 8);
        if (lr == 0) den_part[w][prow] += rs;
      }
    }
    __syncthreads();

    // PV: wave w owns output rows [w*16, w*16+16); accumulate over both halves
#pragma unroll
    for (int ks = 0; ks < 4; ++ks) {
      int kc = ks * 4 + lq;                  // 16B j-chunk 0..15
      int arow = w * 16 + lr;
      short8 aw = *(const short8*)&w_lds[arow * 128 + ((kc ^ (arow & 7)) * 8)];
#pragma unroll
      for (int ct = 0; ct < 4; ++ct) {
        int drow = ct * 16 + lr;
        short8 bv = *(const short8*)&v_t[drow * 128 + ((kc ^ (drow & 7)) * 8)];
        acc_pv[ct] = __builtin_amdgcn_mfma_f32_16x16x32_bf16(aw, bv, acc_pv[ct], 0, 0, 0);
      }
    }
    __syncthreads();
  }

  // epilogue: out = num/den, bf16 store at [row][h*64 + d]
#pragma unroll
  for (int r = 0; r < 4; ++r) {
    int p = w * 16 + lq * 4 + r;
    float den = den_part[0][p] + den_part[1][p] + den_part[2][p] + den_part[3][p] + 1e-10f;
    float inv = 1.0f / den;
#pragma unroll
    for (int ct = 0; ct < 4; ++ct) {
      float ov = acc_pv[ct][r] * inv;
      attout[(qrow0 + p) * 1024 + hc + ct * 16 + lr] = f2bf(ov);
    }
  }
}

extern "C" void kernel_launch(void* const* d_in, const int* in_sizes, int n_in,
                              void* d_out, int out_size, void* d_ws, size_t ws_size,
                              hipStream_t stream) {
  (void)in_sizes; (void)n_in; (void)out_size; (void)ws_size;
  const float* x    = (const float*)d_in[0];
  const float* Wqkv = (const float*)d_in[1];
  const float* Wout = (const float*)d_in[2];
  float* out = (float*)d_out;
  char* ws = (char*)d_ws;

  // workspace layout (80 MB total)
  unsigned short* wqkvb  = (unsigned short*)(ws);               //  6,291,456 B
  unsigned short* woutb  = (unsigned short*)(ws + 6291456);     //  2,097,152 B
  unsigned short* qb     = (unsigned short*)(ws + 8388608);     // 33,554,432 B
  unsigned short* kvb    = (unsigned short*)(ws + 41943040);    //  8,388,608 B
  unsigned short* attout = (unsigned short*)(ws + 50331648);    // 33,554,432 B

  cvt_kernel<<<3072, 256, 0, stream>>>(Wqkv, wqkvb, 3 * 1024 * 1024);
  cvt_kernel<<<1024, 256, 0, stream>>>(Wout, woutb, 1024 * 1024);

  // Q = (x @ Wq^T) * hd^-0.5  -> qb [16384][1024] bf16
  gemm_bt<true, false><<<dim3(128, 8), 256, 0, stream>>>(
      (const void*)x, wqkvb, (void*)qb, 0.125f, 1024, 1024, 1024);
  // K,V only at dilated rows (every 8th global row) -> kvb [2048][2048] bf16
  gemm_bt<true, false><<<dim3(16, 16), 256, 0, stream>>>(
      (const void*)x, wqkvb + 1024 * 1024, (void*)kvb, 1.0f, 8192, 2048, 1024);

  attn_kernel<<<4096, 256, 0, stream>>>(qb, kvb, attout);

  // final projection: out = attout @ Wout^T (f32 output)
  gemm_bt<false, true><<<dim3(128, 8), 256, 0, stream>>>(
      (const void*)attout, woutb, (void*)out, 1.0f, 1024, 1024, 1024);
}

// Round 2
// 263.511 us; speedup vs baseline: 1.0839x; 1.0839x over previous
//
#include <hip/hip_runtime.h>
#include <hip/hip_bf16.h>
#include <stdint.h>

// Problem constants: B=2, M=8192, D=1024, H=16, hd=64, SEG=2048, DIL=8
// => S=4 segments, Kn=256 dilated keys/segment, nb=32 query blocks of 64.
// Dilated key rows are global rows ≡ 0 (mod 8).

typedef __attribute__((ext_vector_type(8))) short short8;
typedef __attribute__((ext_vector_type(4))) float f32x4;
typedef __attribute__((ext_vector_type(4))) unsigned short ushort4v;

#define DEVI static __device__ __forceinline__

DEVI unsigned short f2bf(float f) {
  union { float f; uint32_t u; } v; v.f = f;
  return (unsigned short)((v.u + 0x7FFFu + ((v.u >> 16) & 1u)) >> 16);
}

DEVI void gload_lds16(const void* g, void* l) {
  __builtin_amdgcn_global_load_lds((const __attribute__((address_space(1))) void*)g,
                                   (__attribute__((address_space(3))) void*)l,
                                   16, 0, 0);
}

// ---------------- f32 -> bf16 convert ----------------
__global__ void cvt_kernel(const float* __restrict__ in, unsigned short* __restrict__ out, int n) {
  int i = (blockIdx.x * 256 + threadIdx.x) * 4;
  if (i >= n) return;
  float4 f = *(const float4*)(in + i);
  uint2 o;
  o.x = (uint32_t)f2bf(f.x) | ((uint32_t)f2bf(f.y) << 16);
  o.y = (uint32_t)f2bf(f.z) | ((uint32_t)f2bf(f.w) << 16);
  *(uint2*)(out + i) = o;
}

// ---------------- GEMM: C[m,n] = scale * sum_k A[m,k]*B[n,k] ----------------
// A,B bf16; A row m at A + m*a_row_stride. B [N][K] row-major.
// EPI: 0 = f32 C, 1 = bf16 C, 2 = KV split (tn<8 -> bf16 K rows to Cv;
//      tn>=8 -> V stored TRANSPOSED to Cv2 as [(b*4+s)*1024 + f][256 tokens]).
// 128x128 tile, BK=64, 4 waves, 16x16x32 bf16 MFMA, chunk-XOR swizzled LDS with
// pre-swizzled global source (rule #21: both-sides-or-neither).
template<int EPI>
__global__ __launch_bounds__(256, 2) void gemm_bt(
    const unsigned short* __restrict__ A, const unsigned short* __restrict__ B,
    void* __restrict__ Cv, unsigned short* __restrict__ Cv2,
    float scale, long a_row_stride, int ldc, int K)
{
  __shared__ unsigned short smA[128 * 64];
  __shared__ unsigned short smB[128 * 64];
  const int tid = threadIdx.x;
  const int tm = blockIdx.x, tn = blockIdx.y;
  const int w = tid >> 6, lane = tid & 63;
  const int wr = (w >> 1) * 64, wc = (w & 1) * 64;
  const int lr = lane & 15, lq = lane >> 4;

  int se[4], srow[4], scol[4];
#pragma unroll
  for (int i = 0; i < 4; ++i) {
    int e = (i * 256 + tid) * 8;   // lds element offset of this thread's 16B slot
    int r = e >> 6;                // row 0..127
    int cc = (e >> 3) & 7;         // 16B chunk within row
    se[i] = e; srow[i] = r; scol[i] = (cc ^ (r & 7)) * 8;  // pre-swizzled source col
  }

  f32x4 acc[4][4] = {};

  for (int kt = 0; kt < K / 64; ++kt) {
    if (kt) __syncthreads();
#pragma unroll
    for (int i = 0; i < 4; ++i)
      gload_lds16(A + (long)(tm * 128 + srow[i]) * a_row_stride + kt * 64 + scol[i], &smA[se[i]]);
#pragma unroll
    for (int i = 0; i < 4; ++i)
      gload_lds16(B + (long)(tn * 128 + srow[i]) * K + kt * 64 + scol[i], &smB[se[i]]);
    __syncthreads();

#pragma unroll
    for (int kk = 0; kk < 2; ++kk) {
      int kc = kk * 4 + lq;
      short8 af[4], bfm[4];
#pragma unroll
      for (int i = 0; i < 4; ++i) {
        int row = wr + i * 16 + lr;
        af[i] = *(const short8*)&smA[row * 64 + ((kc ^ (row & 7)) * 8)];
      }
#pragma unroll
      for (int j = 0; j < 4; ++j) {
        int row = wc + j * 16 + lr;
        bfm[j] = *(const short8*)&smB[row * 64 + ((kc ^ (row & 7)) * 8)];
      }
#pragma unroll
      for (int i = 0; i < 4; ++i)
#pragma unroll
        for (int j = 0; j < 4; ++j)
          acc[i][j] = __builtin_amdgcn_mfma_f32_16x16x32_bf16(af[i], bfm[j], acc[i][j], 0, 0, 0);
    }
  }

  if (EPI == 2 && tn >= 8) {
    // V^T store: vtb[(m>>8)*1024 + f][m&255], 4 token-consecutive values -> 8B pack
#pragma unroll
    for (int i = 0; i < 4; ++i) {
      int m0 = tm * 128 + wr + i * 16 + lq * 4;   // token row; (m0>>8) const over r
      long rowbase = (long)(m0 >> 8) * 1024;
#pragma unroll
      for (int j = 0; j < 4; ++j) {
        int f = (tn - 8) * 128 + wc + j * 16 + lr;
        ushort4v p;
#pragma unroll
        for (int r = 0; r < 4; ++r) p[r] = f2bf(acc[i][j][r] * scale);
        *(ushort4v*)&Cv2[(rowbase + f) * 256 + (m0 & 255)] = p;
      }
    }
    return;
  }

#pragma unroll
  for (int i = 0; i < 4; ++i) {
    int rg0 = tm * 128 + wr + i * 16 + lq * 4;
#pragma unroll
    for (int j = 0; j < 4; ++j) {
      int cg = tn * 128 + wc + j * 16 + lr;
#pragma unroll
      for (int r = 0; r < 4; ++r) {
        float v = acc[i][j][r] * scale;
        long off = (long)(rg0 + r) * ldc + cg;
        if (EPI == 0) ((float*)Cv)[off] = v;
        else          ((unsigned short*)Cv)[off] = f2bf(v);
      }
    }
  }
}

// ---------------- segment-local dilated attention ----------------
// One block: 64 queries x 256 keys (two 128-key halves) for one (b,h,s).
// Per-KEY-column max over the 64-query block (exactly per reference), so
// key-halves are independent; num/den just accumulate.
// Q/K fragments and V^T fragments are read directly from global (L1/L2-hot);
// only the P-matrix (w) roundtrips through LDS (layout change C->A fragment).
__global__ __launch_bounds__(256, 4) void attn_kernel(
    const unsigned short* __restrict__ qb,    // [16384][1024] bf16, q*scale
    const unsigned short* __restrict__ kb,    // [2048][1024] bf16 dilated keys
    const unsigned short* __restrict__ vtb,   // [(b*4+s)*1024 + f][256] bf16 V^T
    unsigned short* __restrict__ attout)      // [16384][1024] bf16, col = h*64+d
{
  __shared__ unsigned short w_lds[64 * 128];  // [p][j] swizzled
  __shared__ float den_part[4][64];

  const int bid = blockIdx.x;
  const int mb = bid & 31, s = (bid >> 5) & 3, h = (bid >> 7) & 15, b = bid >> 11;
  const int tid = threadIdx.x, w = tid >> 6, lane = tid & 63;
  const int lr = lane & 15, lq = lane >> 4;
  const long qrow0 = (long)b * 8192 + s * 2048 + mb * 64;
  const int kvrow0 = (b * 4 + s) * 256;
  const int hc = h * 64;

  const unsigned short* qbase = qb + qrow0 * 1024 + hc;
  const unsigned short* kbase = kb + (long)kvrow0 * 1024 + hc;
  const unsigned short* vbase = vtb + ((long)(b * 4 + s) * 1024 + hc) * 256;

  den_part[w][lane] = 0.f;

  f32x4 acc_pv[4] = {};

#pragma unroll
  for (int half = 0; half < 2; ++half) {
    // ---- QK^T: wave w owns score columns [w*32, w*32+32), all 64 query rows
    f32x4 acc_s[4][2] = {};
#pragma unroll
    for (int kk = 0; kk < 2; ++kk) {
      int kc = kk * 4 + lq;
      short8 aq[4], bk[2];
#pragma unroll
      for (int i = 0; i < 4; ++i)
        aq[i] = *(const short8*)&qbase[(i * 16 + lr) * 1024 + kc * 8];
#pragma unroll
      for (int j = 0; j < 2; ++j)
        bk[j] = *(const short8*)&kbase[(half * 128 + w * 32 + j * 16 + lr) * 1024 + kc * 8];
#pragma unroll
      for (int i = 0; i < 4; ++i)
#pragma unroll
        for (int j = 0; j < 2; ++j)
          acc_s[i][j] = __builtin_amdgcn_mfma_f32_16x16x32_bf16(aq[i], bk[j], acc_s[i][j], 0, 0, 0);
    }

    // ---- per-key (column) max over 64 queries
    float cmax[2];
#pragma unroll
    for (int j = 0; j < 2; ++j) {
      float m = -3.4e38f;
#pragma unroll
      for (int i = 0; i < 4; ++i)
#pragma unroll
        for (int r = 0; r < 4; ++r) m = fmaxf(m, acc_s[i][j][r]);
      m = fmaxf(m, __shfl_xor(m, 16));
      m = fmaxf(m, __shfl_xor(m, 32));
      cmax[j] = m;
    }

    // ---- w = exp(s - cmax_col) -> bf16 to w_lds; row sums (den)
#pragma unroll
    for (int i = 0; i < 4; ++i) {
#pragma unroll
      for (int r = 0; r < 4; ++r) {
        int prow = i * 16 + lq * 4 + r;
        float rs = 0.f;
#pragma unroll
        for (int j = 0; j < 2; ++j) {
          float wv = __expf(acc_s[i][j][r] - cmax[j]);
          rs += wv;
          int col = w * 32 + j * 16 + lr;
          w_lds[prow * 128 + (((col >> 3) ^ (prow & 7)) * 8) + (col & 7)] = f2bf(wv);
        }
        rs += __shfl_xor(rs, 1);
        rs += __shfl_xor(rs, 2);
        rs += __shfl_xor(rs, 4);
        rs += __shfl_xor(rs, 8);
        if (lr == 0) den_part[w][prow] += rs;
      }
    }
    __syncthreads();

    // ---- PV: wave w owns output rows [w*16, w*16+16); V^T fragments from global
#pragma unroll
    for (int ks = 0; ks < 4; ++ks) {
      int kc = ks * 4 + lq;                  // 16B j-chunk 0..15
      int arow = w * 16 + lr;
      short8 aw = *(const short8*)&w_lds[arow * 128 + ((kc ^ (arow & 7)) * 8)];
#pragma unroll
      for (int ct = 0; ct < 4; ++ct) {
        short8 bv = *(const short8*)&vbase[(ct * 16 + lr) * 256 + half * 128 + kc * 8];
        acc_pv[ct] = __builtin_amdgcn_mfma_f32_16x16x32_bf16(aw, bv, acc_pv[ct], 0, 0, 0);
      }
    }
    __syncthreads();
  }

  // ---- epilogue: out = num/den
#pragma unroll
  for (int r = 0; r < 4; ++r) {
    int p = w * 16 + lq * 4 + r;
    float den = den_part[0][p] + den_part[1][p] + den_part[2][p] + den_part[3][p] + 1e-10f;
    float inv = 1.0f / den;
#pragma unroll
    for (int ct = 0; ct < 4; ++ct) {
      float ov = acc_pv[ct][r] * inv;
      attout[(qrow0 + p) * 1024 + hc + ct * 16 + lr] = f2bf(ov);
    }
  }
}

extern "C" void kernel_launch(void* const* d_in, const int* in_sizes, int n_in,
                              void* d_out, int out_size, void* d_ws, size_t ws_size,
                              hipStream_t stream) {
  (void)in_sizes; (void)n_in; (void)out_size; (void)ws_size;
  const float* x    = (const float*)d_in[0];
  const float* Wqkv = (const float*)d_in[1];
  const float* Wout = (const float*)d_in[2];
  float* out = (float*)d_out;
  char* ws = (char*)d_ws;

  // workspace layout (80 MB). xb aliases attout: xb is dead before attn writes.
  unsigned short* xb     = (unsigned short*)(ws);               // 33,554,432 B
  unsigned short* attout = (unsigned short*)(ws);               // (same region)
  unsigned short* wqkvb  = (unsigned short*)(ws + 33554432);    //  6,291,456 B
  unsigned short* woutb  = (unsigned short*)(ws + 39845888);    //  2,097,152 B
  unsigned short* qb     = (unsigned short*)(ws + 41943040);    // 33,554,432 B
  unsigned short* kbuf   = (unsigned short*)(ws + 75497472);    //  4,194,304 B
  unsigned short* vtb    = (unsigned short*)(ws + 79691776);    //  4,194,304 B

  cvt_kernel<<<16384, 256, 0, stream>>>(x, xb, 16777216);
  cvt_kernel<<<3072, 256, 0, stream>>>(Wqkv, wqkvb, 3 * 1024 * 1024);
  cvt_kernel<<<1024, 256, 0, stream>>>(Wout, woutb, 1024 * 1024);

  // Q = (x @ Wq^T) * hd^-0.5  -> qb [16384][1024] bf16
  gemm_bt<1><<<dim3(128, 8), 256, 0, stream>>>(
      xb, wqkvb, (void*)qb, nullptr, 0.125f, 1024, 1024, 1024);
  // K,V at dilated rows (every 8th): K -> kbuf [2048][1024], V -> vtb transposed
  gemm_bt<2><<<dim3(16, 16), 256, 0, stream>>>(
      xb, wqkvb + 1024 * 1024, (void*)kbuf, vtb, 1.0f, 8192, 1024, 1024);

  attn_kernel<<<4096, 256, 0, stream>>>(qb, kbuf, vtb, attout);

  // final projection: out = attout @ Wout^T (f32 output)
  gemm_bt<0><<<dim3(128, 8), 256, 0, stream>>>(
      attout, woutb, (void*)out, nullptr, 1.0f, 1024, 1024, 1024);
}

// Round 3
// 200.982 us; speedup vs baseline: 1.4212x; 1.3111x over previous
//
#include <hip/hip_runtime.h>
#include <hip/hip_bf16.h>
#include <stdint.h>

// Problem constants: B=2, M=8192, D=1024, H=16, hd=64, SEG=2048, DIL=8
// => S=4 segments, Kn=256 dilated keys/segment, nb=32 query blocks of 64.

typedef __attribute__((ext_vector_type(8))) short short8;
typedef __attribute__((ext_vector_type(4))) float f32x4;
typedef __attribute__((ext_vector_type(4))) unsigned short ushort4v;

#define DEVI static __device__ __forceinline__

DEVI unsigned short f2bf(float f) {
  union { float f; uint32_t u; } v; v.f = f;
  return (unsigned short)((v.u + 0x7FFFu + ((v.u >> 16) & 1u)) >> 16);
}

DEVI void gload_lds16(const void* g, void* l) {
  __builtin_amdgcn_global_load_lds((const __attribute__((address_space(1))) void*)g,
                                   (__attribute__((address_space(3))) void*)l,
                                   16, 0, 0);
}

// ---------------- f32 -> bf16 convert ----------------
__global__ void cvt_kernel(const float* __restrict__ in, unsigned short* __restrict__ out, int n) {
  int i = (blockIdx.x * 256 + threadIdx.x) * 4;
  if (i >= n) return;
  float4 f = *(const float4*)(in + i);
  uint2 o;
  o.x = (uint32_t)f2bf(f.x) | ((uint32_t)f2bf(f.y) << 16);
  o.y = (uint32_t)f2bf(f.z) | ((uint32_t)f2bf(f.w) << 16);
  *(uint2*)(out + i) = o;
}

// ---------------- GEMM: C[m,n] = scale * sum_k A[m,k]*B[n,k] ----------------
// A,B bf16; A row m at A + m*a_row_stride. B [N][K] row-major.
// EPI: 0 = f32 C, 1 = bf16 C, 2 = KV split (tn<8 -> bf16 K rows to Cv;
//      tn>=8 -> V stored TRANSPOSED to Cv2 as [(b*4+s)*1024 + f][256 tokens]).
template<int EPI>
__global__ __launch_bounds__(256, 2) void gemm_bt(
    const unsigned short* __restrict__ A, const unsigned short* __restrict__ B,
    void* __restrict__ Cv, unsigned short* __restrict__ Cv2,
    float scale, long a_row_stride, int ldc, int K)
{
  __shared__ unsigned short smA[128 * 64];
  __shared__ unsigned short smB[128 * 64];
  const int tid = threadIdx.x;
  const int tm = blockIdx.x, tn = blockIdx.y;
  const int w = tid >> 6, lane = tid & 63;
  const int wr = (w >> 1) * 64, wc = (w & 1) * 64;
  const int lr = lane & 15, lq = lane >> 4;

  int se[4], srow[4], scol[4];
#pragma unroll
  for (int i = 0; i < 4; ++i) {
    int e = (i * 256 + tid) * 8;
    int r = e >> 6;
    int cc = (e >> 3) & 7;
    se[i] = e; srow[i] = r; scol[i] = (cc ^ (r & 7)) * 8;
  }

  f32x4 acc[4][4] = {};

  for (int kt = 0; kt < K / 64; ++kt) {
    if (kt) __syncthreads();
#pragma unroll
    for (int i = 0; i < 4; ++i)
      gload_lds16(A + (long)(tm * 128 + srow[i]) * a_row_stride + kt * 64 + scol[i], &smA[se[i]]);
#pragma unroll
    for (int i = 0; i < 4; ++i)
      gload_lds16(B + (long)(tn * 128 + srow[i]) * K + kt * 64 + scol[i], &smB[se[i]]);
    __syncthreads();

#pragma unroll
    for (int kk = 0; kk < 2; ++kk) {
      int kc = kk * 4 + lq;
      short8 af[4], bfm[4];
#pragma unroll
      for (int i = 0; i < 4; ++i) {
        int row = wr + i * 16 + lr;
        af[i] = *(const short8*)&smA[row * 64 + ((kc ^ (row & 7)) * 8)];
      }
#pragma unroll
      for (int j = 0; j < 4; ++j) {
        int row = wc + j * 16 + lr;
        bfm[j] = *(const short8*)&smB[row * 64 + ((kc ^ (row & 7)) * 8)];
      }
#pragma unroll
      for (int i = 0; i < 4; ++i)
#pragma unroll
        for (int j = 0; j < 4; ++j)
          acc[i][j] = __builtin_amdgcn_mfma_f32_16x16x32_bf16(af[i], bfm[j], acc[i][j], 0, 0, 0);
    }
  }

  if (EPI == 2 && tn >= 8) {
#pragma unroll
    for (int i = 0; i < 4; ++i) {
      int m0 = tm * 128 + wr + i * 16 + lq * 4;
      long rowbase = (long)(m0 >> 8) * 1024;
#pragma unroll
      for (int j = 0; j < 4; ++j) {
        int f = (tn - 8) * 128 + wc + j * 16 + lr;
        ushort4v p;
#pragma unroll
        for (int r = 0; r < 4; ++r) p[r] = f2bf(acc[i][j][r] * scale);
        *(ushort4v*)&Cv2[(rowbase + f) * 256 + (m0 & 255)] = p;
      }
    }
    return;
  }

#pragma unroll
  for (int i = 0; i < 4; ++i) {
    int rg0 = tm * 128 + wr + i * 16 + lq * 4;
#pragma unroll
    for (int j = 0; j < 4; ++j) {
      int cg = tn * 128 + wc + j * 16 + lr;
#pragma unroll
      for (int r = 0; r < 4; ++r) {
        float v = acc[i][j][r] * scale;
        long off = (long)(rg0 + r) * ldc + cg;
        if (EPI == 0) ((float*)Cv)[off] = v;
        else          ((unsigned short*)Cv)[off] = f2bf(v);
      }
    }
  }
}

// ---------------- segment-local dilated attention ----------------
// One block: 512 queries (8 query-blocks of 64) x 256 keys for one (b,h,s,quarter).
// K [256][64] and V^T [64][256] staged in LDS ONCE (swizzled via pre-swizzled
// global source), then 8 query-block loop. Per-KEY-column max over each
// 64-query block exactly per reference. den is accumulated by an extra MFMA
// with an all-ones A operand (same bf16 weights as num -> error cancellation).
// PV computed as D[f][q] = mfma(A=V^T frag, B=w frag) so each lane holds 4
// consecutive f for a fixed q -> packed 8B output stores, den in-lane.
__global__ __launch_bounds__(256, 2) void attn_kernel(
    const unsigned short* __restrict__ qb,    // [16384][1024] bf16, q*scale
    const unsigned short* __restrict__ kb,    // [2048][1024] bf16 dilated keys
    const unsigned short* __restrict__ vtb,   // [(b*4+s)*1024 + f][256] bf16 V^T
    unsigned short* __restrict__ attout)      // [16384][1024] bf16, col = h*64+d
{
  __shared__ unsigned short k_t[256 * 64];    // [j][d]  swizzled, 32 KB
  __shared__ unsigned short v_t[64 * 256];    // [f][j]  swizzled, 32 KB
  __shared__ unsigned short w_lds[64 * 128];  // [q][j_half] swizzled, 16 KB

  const int bid = blockIdx.x;
  const int quarter = bid & 3, s = (bid >> 2) & 3, h = (bid >> 4) & 15, b = bid >> 8;
  const int tid = threadIdx.x, w = tid >> 6, lane = tid & 63;
  const int lr = lane & 15, lq = lane >> 4;
  const long qrow0 = (long)b * 8192 + s * 2048 + quarter * 512;
  const int hc = h * 64;

  const unsigned short* kbase = kb + ((long)(b * 4 + s) * 256) * 1024 + hc;
  const unsigned short* vbase = vtb + ((long)(b * 4 + s) * 1024 + hc) * 256;

  // ---- stage K [256][64] and V^T [64][256], chunk-XOR swizzled
#pragma unroll
  for (int it = 0; it < 8; ++it) {
    int e = (it * 256 + tid) * 8;
    int row = e >> 6;
    int ch = (e >> 3) & 7;
    gload_lds16(kbase + (long)row * 1024 + ((ch ^ (row & 7)) * 8), &k_t[e]);
  }
#pragma unroll
  for (int it = 0; it < 8; ++it) {
    int e = (it * 256 + tid) * 8;
    int f = e >> 8;
    int ch = (e >> 3) & 31;
    gload_lds16(vbase + (long)f * 256 + ((ch ^ (f & 7)) * 8), &v_t[e]);
  }
  __syncthreads();

  short8 ones;
#pragma unroll
  for (int e = 0; e < 8; ++e) ones[e] = (short)0x3F80;  // bf16 1.0

  for (int qblk = 0; qblk < 8; ++qblk) {
    const unsigned short* qbase = qb + (qrow0 + qblk * 64) * 1024 + hc;
    f32x4 acc_pv[4] = {};
    f32x4 acc_den = {};

#pragma unroll
    for (int half = 0; half < 2; ++half) {
      // ---- QK^T: wave w owns key cols [half*128 + w*32, +32)
      f32x4 acc_s[4][2] = {};
#pragma unroll
      for (int kk = 0; kk < 2; ++kk) {
        int kc = kk * 4 + lq;
        short8 aq[4], bk[2];
#pragma unroll
        for (int i = 0; i < 4; ++i)
          aq[i] = *(const short8*)&qbase[(i * 16 + lr) * 1024 + kc * 8];
#pragma unroll
        for (int j = 0; j < 2; ++j) {
          int row = half * 128 + w * 32 + j * 16 + lr;
          bk[j] = *(const short8*)&k_t[row * 64 + ((kc ^ (row & 7)) * 8)];
        }
#pragma unroll
        for (int i = 0; i < 4; ++i)
#pragma unroll
          for (int j = 0; j < 2; ++j)
            acc_s[i][j] = __builtin_amdgcn_mfma_f32_16x16x32_bf16(aq[i], bk[j], acc_s[i][j], 0, 0, 0);
      }

      // ---- per-key (column) max over the 64-query block
      float cmax[2];
#pragma unroll
      for (int j = 0; j < 2; ++j) {
        float m = -3.4e38f;
#pragma unroll
        for (int i = 0; i < 4; ++i)
#pragma unroll
          for (int r = 0; r < 4; ++r) m = fmaxf(m, acc_s[i][j][r]);
        m = fmaxf(m, __shfl_xor(m, 16));
        m = fmaxf(m, __shfl_xor(m, 32));
        cmax[j] = m;
      }

      // ---- w = exp(s - cmax_col) -> bf16 into w_lds [64][128] swizzled
#pragma unroll
      for (int i = 0; i < 4; ++i) {
#pragma unroll
        for (int r = 0; r < 4; ++r) {
          int q = i * 16 + lq * 4 + r;
#pragma unroll
          for (int jf = 0; jf < 2; ++jf) {
            int col = w * 32 + jf * 16 + lr;
            float wv = __expf(acc_s[i][jf][r] - cmax[jf]);
            w_lds[q * 128 + ((((col >> 3) ^ (q & 7)) << 3) | (col & 7))] = f2bf(wv);
          }
        }
      }
      __syncthreads();

      // ---- PV: wave w owns queries [w*16, +16); den via ones-MFMA
#pragma unroll
      for (int ks = 0; ks < 4; ++ks) {
        int kc = ks * 4 + lq;
        int qrow = w * 16 + lr;
        short8 bw = *(const short8*)&w_lds[qrow * 128 + ((kc ^ (lr & 7)) << 3)];
        acc_den = __builtin_amdgcn_mfma_f32_16x16x32_bf16(ones, bw, acc_den, 0, 0, 0);
#pragma unroll
        for (int ct = 0; ct < 4; ++ct) {
          int frow = ct * 16 + lr;
          short8 av = *(const short8*)&v_t[frow * 256 + (((half * 16 + kc) ^ (lr & 7)) << 3)];
          acc_pv[ct] = __builtin_amdgcn_mfma_f32_16x16x32_bf16(av, bw, acc_pv[ct], 0, 0, 0);
        }
      }
      __syncthreads();
    }

    // ---- epilogue: out[q][f] = num/den, packed 8B stores
    float inv = 1.0f / (acc_den[0] + 1e-10f);
    long orow = (qrow0 + qblk * 64 + w * 16 + lr) * 1024 + hc;
#pragma unroll
    for (int ct = 0; ct < 4; ++ct) {
      ushort4v p;
#pragma unroll
      for (int r = 0; r < 4; ++r) p[r] = f2bf(acc_pv[ct][r] * inv);
      *(ushort4v*)&attout[orow + ct * 16 + lq * 4] = p;
    }
  }
}

extern "C" void kernel_launch(void* const* d_in, const int* in_sizes, int n_in,
                              void* d_out, int out_size, void* d_ws, size_t ws_size,
                              hipStream_t stream) {
  (void)in_sizes; (void)n_in; (void)out_size; (void)ws_size;
  const float* x    = (const float*)d_in[0];
  const float* Wqkv = (const float*)d_in[1];
  const float* Wout = (const float*)d_in[2];
  float* out = (float*)d_out;
  char* ws = (char*)d_ws;

  // workspace layout (80 MB). xb aliases attout: xb is dead before attn writes.
  unsigned short* xb     = (unsigned short*)(ws);               // 33,554,432 B
  unsigned short* attout = (unsigned short*)(ws);               // (same region)
  unsigned short* wqkvb  = (unsigned short*)(ws + 33554432);    //  6,291,456 B
  unsigned short* woutb  = (unsigned short*)(ws + 39845888);    //  2,097,152 B
  unsigned short* qbuf   = (unsigned short*)(ws + 41943040);    // 33,554,432 B
  unsigned short* kbuf   = (unsigned short*)(ws + 75497472);    //  4,194,304 B
  unsigned short* vtb    = (unsigned short*)(ws + 79691776);    //  4,194,304 B

  cvt_kernel<<<16384, 256, 0, stream>>>(x, xb, 16777216);
  cvt_kernel<<<3072, 256, 0, stream>>>(Wqkv, wqkvb, 3 * 1024 * 1024);
  cvt_kernel<<<1024, 256, 0, stream>>>(Wout, woutb, 1024 * 1024);

  // Q = (x @ Wq^T) * hd^-0.5  -> qbuf [16384][1024] bf16
  gemm_bt<1><<<dim3(128, 8), 256, 0, stream>>>(
      xb, wqkvb, (void*)qbuf, nullptr, 0.125f, 1024, 1024, 1024);
  // K,V at dilated rows (every 8th): K -> kbuf [2048][1024], V -> vtb transposed
  gemm_bt<2><<<dim3(16, 16), 256, 0, stream>>>(
      xb, wqkvb + 1024 * 1024, (void*)kbuf, vtb, 1.0f, 8192, 1024, 1024);

  attn_kernel<<<512, 256, 0, stream>>>(qbuf, kbuf, vtb, attout);

  // final projection: out = attout @ Wout^T (f32 output)
  gemm_bt<0><<<dim3(128, 8), 256, 0, stream>>>(
      attout, woutb, (void*)out, nullptr, 1.0f, 1024, 1024, 1024);
}

// Round 5
// 198.161 us; speedup vs baseline: 1.4414x; 1.0142x over previous
//
#include <hip/hip_runtime.h>
#include <hip/hip_bf16.h>
#include <stdint.h>

// Problem constants: B=2, M=8192, D=1024, H=16, hd=64, SEG=2048, DIL=8
// => S=4 segments, Kn=256 dilated keys/segment, nb=32 query blocks of 64.

typedef __attribute__((ext_vector_type(8))) short short8;
typedef __attribute__((ext_vector_type(4))) float f32x4;
typedef __attribute__((ext_vector_type(4))) unsigned short ushort4v;

#define DEVI static __device__ __forceinline__

DEVI unsigned short f2bf(float f) {
  union { float f; uint32_t u; } v; v.f = f;
  return (unsigned short)((v.u + 0x7FFFu + ((v.u >> 16) & 1u)) >> 16);
}

// Pure-C bf16 pair pack (bisect: replaces v_cvt_pk_bf16_f32 inline asm).
// lo -> bits[15:0], hi -> bits[31:16].
DEVI uint32_t pack_bf16(float lo, float hi) {
  return (uint32_t)f2bf(lo) | ((uint32_t)f2bf(hi) << 16);
}

DEVI void gload_lds16(const void* g, void* l) {
  __builtin_amdgcn_global_load_lds((const __attribute__((address_space(1))) void*)g,
                                   (__attribute__((address_space(3))) void*)l,
                                   16, 0, 0);
}

// ---------------- f32 -> bf16 convert ----------------
__global__ void cvt_kernel(const float* __restrict__ in, unsigned short* __restrict__ out, int n) {
  int i = (blockIdx.x * 256 + threadIdx.x) * 4;
  if (i >= n) return;
  float4 f = *(const float4*)(in + i);
  uint2 o;
  o.x = (uint32_t)f2bf(f.x) | ((uint32_t)f2bf(f.y) << 16);
  o.y = (uint32_t)f2bf(f.z) | ((uint32_t)f2bf(f.w) << 16);
  *(uint2*)(out + i) = o;
}

// ---------------- GEMM: C[m,n] = scale * sum_k A[m,k]*B[n,k] ----------------
// A,B bf16; A row m at A + m*a_row_stride. B [N][K] row-major.
// EPI: 0 = f32 C, 1 = bf16 C, 2 = KV split (tn<8 -> bf16 K rows to Cv;
//      tn>=8 -> V stored TRANSPOSED + sigma-permuted to Cv2:
//      row = seg*1024 + f, 128 u32 token-cols per segment; u32 col c packs
//      tokens (32*(c>>4) + (c&15), +16) of the segment -- matching the
//      attention kernel's packed w-writes.)
template<int EPI>
__global__ __launch_bounds__(256, 2) void gemm_bt(
    const unsigned short* __restrict__ A, const unsigned short* __restrict__ B,
    void* __restrict__ Cv, unsigned short* __restrict__ Cv2,
    float scale, long a_row_stride, int ldc, int K)
{
  __shared__ unsigned short smA[128 * 64];
  __shared__ unsigned short smB[128 * 64];
  const int tid = threadIdx.x;
  const int tm = blockIdx.x, tn = blockIdx.y;
  const int w = tid >> 6, lane = tid & 63;
  const int wr = (w >> 1) * 64, wc = (w & 1) * 64;
  const int lr = lane & 15, lq = lane >> 4;

  int se[4], srow[4], scol[4];
#pragma unroll
  for (int i = 0; i < 4; ++i) {
    int e = (i * 256 + tid) * 8;
    int r = e >> 6;
    int cc = (e >> 3) & 7;
    se[i] = e; srow[i] = r; scol[i] = (cc ^ (r & 7)) * 8;
  }

  f32x4 acc[4][4] = {};

  for (int kt = 0; kt < K / 64; ++kt) {
    if (kt) __syncthreads();
#pragma unroll
    for (int i = 0; i < 4; ++i)
      gload_lds16(A + (long)(tm * 128 + srow[i]) * a_row_stride + kt * 64 + scol[i], &smA[se[i]]);
#pragma unroll
    for (int i = 0; i < 4; ++i)
      gload_lds16(B + (long)(tn * 128 + srow[i]) * K + kt * 64 + scol[i], &smB[se[i]]);
    __syncthreads();

#pragma unroll
    for (int kk = 0; kk < 2; ++kk) {
      int kc = kk * 4 + lq;
      short8 af[4], bfm[4];
#pragma unroll
      for (int i = 0; i < 4; ++i) {
        int row = wr + i * 16 + lr;
        af[i] = *(const short8*)&smA[row * 64 + ((kc ^ (row & 7)) * 8)];
      }
#pragma unroll
      for (int j = 0; j < 4; ++j) {
        int row = wc + j * 16 + lr;
        bfm[j] = *(const short8*)&smB[row * 64 + ((kc ^ (row & 7)) * 8)];
      }
#pragma unroll
      for (int i = 0; i < 4; ++i)
#pragma unroll
        for (int j = 0; j < 4; ++j)
          acc[i][j] = __builtin_amdgcn_mfma_f32_16x16x32_bf16(af[i], bfm[j], acc[i][j], 0, 0, 0);
    }
  }

  if (EPI == 2 && tn >= 8) {
    // sigma-permuted V^T store: pair fragments (ip, ip+1) hold tokens (t, t+16)
    const int fbase = (tn - 8) * 128 + wc;
#pragma unroll
    for (int ip = 0; ip < 4; ip += 2) {
      int t0 = tm * 128 + wr + ip * 16 + lq * 4;   // token of reg r=0 (even frag)
      int seg = t0 >> 8;
      int ts  = t0 & 255;
      int c32 = (ts >> 5) * 16 + (ts & 15);        // u32 col for r=0
#pragma unroll
      for (int j = 0; j < 4; ++j) {
        int f = fbase + j * 16 + lr;
        uint32_t* rp = (uint32_t*)&Cv2[((long)(seg * 1024 + f)) * 256];
        uint4 U;
        U.x = pack_bf16(acc[ip][j][0] * scale, acc[ip + 1][j][0] * scale);
        U.y = pack_bf16(acc[ip][j][1] * scale, acc[ip + 1][j][1] * scale);
        U.z = pack_bf16(acc[ip][j][2] * scale, acc[ip + 1][j][2] * scale);
        U.w = pack_bf16(acc[ip][j][3] * scale, acc[ip + 1][j][3] * scale);
        *(uint4*)&rp[c32] = U;
      }
    }
    return;
  }

#pragma unroll
  for (int i = 0; i < 4; ++i) {
    int rg0 = tm * 128 + wr + i * 16 + lq * 4;
#pragma unroll
    for (int j = 0; j < 4; ++j) {
      int cg = tn * 128 + wc + j * 16 + lr;
#pragma unroll
      for (int r = 0; r < 4; ++r) {
        float v = acc[i][j][r] * scale;
        long off = (long)(rg0 + r) * ldc + cg;
        if (EPI == 0) ((float*)Cv)[off] = v;
        else          ((unsigned short*)Cv)[off] = f2bf(v);
      }
    }
  }
}

// ---------------- segment-local dilated attention ----------------
// One block: 256 queries (4 query-blocks of 64) x 256 keys for one (b,h,s,eighth).
// K fragments live in REGISTERS (loaded once per block). V^T [64f][256g] staged
// in LDS once (sigma-permuted global layout, chunk-XOR swizzle). Per-KEY-column
// max over each 64-query block per reference. w written as packed u32 pairs
// into [64 q][68-stride u32] LDS. den via ones-MFMA (same bf16 weights as num).
// PV: D[f][q] = mfma(A=V^T frag, B=w frag) -> packed 8B output stores.
__global__ __launch_bounds__(256, 3) void attn_kernel(
    const unsigned short* __restrict__ qb,    // [16384][1024] bf16, q*scale
    const unsigned short* __restrict__ kb,    // [2048][1024] bf16 dilated keys
    const unsigned short* __restrict__ vtb,   // sigma-permuted V^T
    unsigned short* __restrict__ attout)      // [16384][1024] bf16, col = h*64+d
{
  __shared__ unsigned short v_t[64 * 256];    // [f][g] swizzled, 32 KB
  __shared__ uint32_t w32[64 * 68];           // [q][col], stride 68, 17.4 KB

  // XCD-grouping remap (bijective): XCD k = blockIdx%8 gets contiguous work
  // chunk k*128.. so same-(b,s) KV stays in one XCD's L2.
  const int u = (blockIdx.x & 7) * 128 + (blockIdx.x >> 3);
  const int e8 = u & 7, h = (u >> 3) & 15, s = (u >> 7) & 3, b = u >> 9;
  const int tid = threadIdx.x, w = tid >> 6, lane = tid & 63;
  const int lr = lane & 15, lq = lane >> 4;
  const long qrow0 = (long)b * 8192 + s * 2048 + e8 * 256;
  const int hc = h * 64;

  const unsigned short* kbase = kb + ((long)(b * 4 + s) * 256) * 1024 + hc;
  const unsigned short* vbase = vtb + ((long)(b * 4 + s) * 1024 + hc) * 256;

  // ---- stage V^T [64][256] (chunk-XOR swizzled; global order already sigma)
#pragma unroll
  for (int it = 0; it < 8; ++it) {
    int e = (it * 256 + tid) * 8;
    int f = e >> 8;
    int ch = (e >> 3) & 31;
    gload_lds16(vbase + (long)f * 256 + ((ch ^ (f & 7)) * 8), &v_t[e]);
  }

  // ---- K fragments -> registers (persistent, 8 x b128)
  short8 bk[2][2][2];   // [half][kk][jf]
#pragma unroll
  for (int half = 0; half < 2; ++half)
#pragma unroll
    for (int kk = 0; kk < 2; ++kk)
#pragma unroll
      for (int jf = 0; jf < 2; ++jf)
        bk[half][kk][jf] = *(const short8*)
          &kbase[(long)(half * 128 + w * 32 + jf * 16 + lr) * 1024 + (kk * 4 + lq) * 8];

  __syncthreads();

  short8 ones;
#pragma unroll
  for (int e = 0; e < 8; ++e) ones[e] = (short)0x3F80;  // bf16 1.0

  for (int qblk = 0; qblk < 4; ++qblk) {
    const unsigned short* qbase = qb + (qrow0 + qblk * 64) * 1024 + hc;
    f32x4 acc_pv[4] = {};
    f32x4 acc_den = {};

#pragma unroll
    for (int half = 0; half < 2; ++half) {
      // ---- QK^T: wave w owns key cols [half*128 + w*32, +32)
      f32x4 acc_s[4][2] = {};
#pragma unroll
      for (int kk = 0; kk < 2; ++kk) {
        int kc = kk * 4 + lq;
        short8 aq[4];
#pragma unroll
        for (int i = 0; i < 4; ++i)
          aq[i] = *(const short8*)&qbase[(i * 16 + lr) * 1024 + kc * 8];
#pragma unroll
        for (int i = 0; i < 4; ++i)
#pragma unroll
          for (int j = 0; j < 2; ++j)
            acc_s[i][j] = __builtin_amdgcn_mfma_f32_16x16x32_bf16(aq[i], bk[half][kk][j], acc_s[i][j], 0, 0, 0);
      }

      // ---- per-key (column) max over the 64-query block
      float cmax[2];
#pragma unroll
      for (int j = 0; j < 2; ++j) {
        float m = -3.4e38f;
#pragma unroll
        for (int i = 0; i < 4; ++i)
#pragma unroll
          for (int r = 0; r < 4; ++r) m = fmaxf(m, acc_s[i][j][r]);
        m = fmaxf(m, __shfl_xor(m, 16));
        m = fmaxf(m, __shfl_xor(m, 32));
        cmax[j] = m;
      }

      // ---- w = exp(s - cmax_col): packed u32 (keys w*32+lr / +16) -> w32[q][w*16+lr]
#pragma unroll
      for (int i = 0; i < 4; ++i) {
#pragma unroll
        for (int r = 0; r < 4; ++r) {
          int q = i * 16 + lq * 4 + r;
          uint32_t pk = pack_bf16(__expf(acc_s[i][0][r] - cmax[0]),
                                  __expf(acc_s[i][1][r] - cmax[1]));
          w32[q * 68 + w * 16 + lr] = pk;
        }
      }
      __syncthreads();

      // ---- PV: wave w owns queries [w*16, +16); den via ones-MFMA
#pragma unroll
      for (int ks = 0; ks < 4; ++ks) {
        int kc = ks * 4 + lq;
        short8 bw = *(const short8*)&w32[(w * 16 + lr) * 68 + kc * 4];
        acc_den = __builtin_amdgcn_mfma_f32_16x16x32_bf16(ones, bw, acc_den, 0, 0, 0);
#pragma unroll
        for (int ct = 0; ct < 4; ++ct) {
          int frow = ct * 16 + lr;
          short8 av = *(const short8*)&v_t[frow * 256 + (((half * 16 + kc) ^ (lr & 7)) << 3)];
          acc_pv[ct] = __builtin_amdgcn_mfma_f32_16x16x32_bf16(av, bw, acc_pv[ct], 0, 0, 0);
        }
      }
      __syncthreads();
    }

    // ---- epilogue: out[q][f] = num/den, packed 8B stores
    float inv = 1.0f / (acc_den[0] + 1e-10f);
    long orow = (qrow0 + qblk * 64 + w * 16 + lr) * 1024 + hc;
#pragma unroll
    for (int ct = 0; ct < 4; ++ct) {
      ushort4v p;
#pragma unroll
      for (int r = 0; r < 4; ++r) p[r] = f2bf(acc_pv[ct][r] * inv);
      *(ushort4v*)&attout[orow + ct * 16 + lq * 4] = p;
    }
  }
}

extern "C" void kernel_launch(void* const* d_in, const int* in_sizes, int n_in,
                              void* d_out, int out_size, void* d_ws, size_t ws_size,
                              hipStream_t stream) {
  (void)in_sizes; (void)n_in; (void)out_size; (void)ws_size;
  const float* x    = (const float*)d_in[0];
  const float* Wqkv = (const float*)d_in[1];
  const float* Wout = (const float*)d_in[2];
  float* out = (float*)d_out;
  char* ws = (char*)d_ws;

  // workspace layout (80 MB). xb aliases attout: xb is dead before attn writes.
  unsigned short* xb     = (unsigned short*)(ws);               // 33,554,432 B
  unsigned short* attout = (unsigned short*)(ws);               // (same region)
  unsigned short* wqkvb  = (unsigned short*)(ws + 33554432);    //  6,291,456 B
  unsigned short* woutb  = (unsigned short*)(ws + 39845888);    //  2,097,152 B
  unsigned short* qbuf   = (unsigned short*)(ws + 41943040);    // 33,554,432 B
  unsigned short* kbuf   = (unsigned short*)(ws + 75497472);    //  4,194,304 B
  unsigned short* vtb    = (unsigned short*)(ws + 79691776);    //  4,194,304 B

  cvt_kernel<<<16384, 256, 0, stream>>>(x, xb, 16777216);
  cvt_kernel<<<3072, 256, 0, stream>>>(Wqkv, wqkvb, 3 * 1024 * 1024);
  cvt_kernel<<<1024, 256, 0, stream>>>(Wout, woutb, 1024 * 1024);

  // Q = (x @ Wq^T) * hd^-0.5  -> qbuf [16384][1024] bf16
  gemm_bt<1><<<dim3(128, 8), 256, 0, stream>>>(
      xb, wqkvb, (void*)qbuf, nullptr, 0.125f, 1024, 1024, 1024);
  // K,V at dilated rows (every 8th): K -> kbuf [2048][1024], V -> vtb (sigma V^T)
  gemm_bt<2><<<dim3(16, 16), 256, 0, stream>>>(
      xb, wqkvb + 1024 * 1024, (void*)kbuf, vtb, 1.0f, 8192, 1024, 1024);

  attn_kernel<<<1024, 256, 0, stream>>>(qbuf, kbuf, vtb, attout);

  // final projection: out = attout @ Wout^T (f32 output)
  gemm_bt<0><<<dim3(128, 8), 256, 0, stream>>>(
      attout, woutb, (void*)out, nullptr, 1.0f, 1024, 1024, 1024);
}

// Round 6
// 184.102 us; speedup vs baseline: 1.5515x; 1.0764x over previous
//
#include <hip/hip_runtime.h>
#include <hip/hip_bf16.h>
#include <stdint.h>

// Problem constants: B=2, M=8192, D=1024, H=16, hd=64, SEG=2048, DIL=8
// => S=4 segments, Kn=256 dilated keys/segment, nb=32 query blocks of 64.

typedef __attribute__((ext_vector_type(8))) short short8;
typedef __attribute__((ext_vector_type(4))) float f32x4;
typedef __attribute__((ext_vector_type(4))) unsigned short ushort4v;

#define DEVI static __device__ __forceinline__

DEVI unsigned short f2bf(float f) {
  union { float f; uint32_t u; } v; v.f = f;
  return (unsigned short)((v.u + 0x7FFFu + ((v.u >> 16) & 1u)) >> 16);
}

// Pure-C bf16 pair pack (v_cvt_pk_bf16_f32 inline asm was broken - round 4/5).
DEVI uint32_t pack_bf16(float lo, float hi) {
  return (uint32_t)f2bf(lo) | ((uint32_t)f2bf(hi) << 16);
}

DEVI void gload_lds16(const void* g, void* l) {
  __builtin_amdgcn_global_load_lds((const __attribute__((address_space(1))) void*)g,
                                   (__attribute__((address_space(3))) void*)l,
                                   16, 0, 0);
}

// ---------------- f32 -> bf16 convert ----------------
__global__ void cvt_kernel(const float* __restrict__ in, unsigned short* __restrict__ out, int n) {
  int i = (blockIdx.x * 256 + threadIdx.x) * 4;
  if (i >= n) return;
  float4 f = *(const float4*)(in + i);
  uint2 o;
  o.x = (uint32_t)f2bf(f.x) | ((uint32_t)f2bf(f.y) << 16);
  o.y = (uint32_t)f2bf(f.z) | ((uint32_t)f2bf(f.w) << 16);
  *(uint2*)(out + i) = o;
}

// ---------------- GEMM: C[m,n] = scale * sum_k A[m,k]*B[n,k] ----------------
// A,B bf16; A row m at A + m*a_row_stride. B [N][K] row-major.
// EPI: 0 = f32 C, 1 = bf16 C, 2 = KV split (tn<8 -> bf16 K rows to Cv;
//      tn>=8 -> V stored TRANSPOSED + sigma-permuted to Cv2:
//      row = seg*1024 + f, 128 u32 token-cols per segment; u32 col c packs
//      tokens (32*(c>>4) + (c&15), +16) -- matching attn's packed w-writes.)
template<int EPI>
__global__ __launch_bounds__(256, 2) void gemm_bt(
    const unsigned short* __restrict__ A, const unsigned short* __restrict__ B,
    void* __restrict__ Cv, unsigned short* __restrict__ Cv2,
    float scale, long a_row_stride, int ldc, int K)
{
  __shared__ unsigned short smA[128 * 64];
  __shared__ unsigned short smB[128 * 64];
  const int tid = threadIdx.x;
  const int tm = blockIdx.x, tn = blockIdx.y;
  const int w = tid >> 6, lane = tid & 63;
  const int wr = (w >> 1) * 64, wc = (w & 1) * 64;
  const int lr = lane & 15, lq = lane >> 4;

  int se[4], srow[4], scol[4];
#pragma unroll
  for (int i = 0; i < 4; ++i) {
    int e = (i * 256 + tid) * 8;
    int r = e >> 6;
    int cc = (e >> 3) & 7;
    se[i] = e; srow[i] = r; scol[i] = (cc ^ (r & 7)) * 8;
  }

  f32x4 acc[4][4] = {};

  for (int kt = 0; kt < K / 64; ++kt) {
    if (kt) __syncthreads();
#pragma unroll
    for (int i = 0; i < 4; ++i)
      gload_lds16(A + (long)(tm * 128 + srow[i]) * a_row_stride + kt * 64 + scol[i], &smA[se[i]]);
#pragma unroll
    for (int i = 0; i < 4; ++i)
      gload_lds16(B + (long)(tn * 128 + srow[i]) * K + kt * 64 + scol[i], &smB[se[i]]);
    __syncthreads();

#pragma unroll
    for (int kk = 0; kk < 2; ++kk) {
      int kc = kk * 4 + lq;
      short8 af[4], bfm[4];
#pragma unroll
      for (int i = 0; i < 4; ++i) {
        int row = wr + i * 16 + lr;
        af[i] = *(const short8*)&smA[row * 64 + ((kc ^ (row & 7)) * 8)];
      }
#pragma unroll
      for (int j = 0; j < 4; ++j) {
        int row = wc + j * 16 + lr;
        bfm[j] = *(const short8*)&smB[row * 64 + ((kc ^ (row & 7)) * 8)];
      }
#pragma unroll
      for (int i = 0; i < 4; ++i)
#pragma unroll
        for (int j = 0; j < 4; ++j)
          acc[i][j] = __builtin_amdgcn_mfma_f32_16x16x32_bf16(af[i], bfm[j], acc[i][j], 0, 0, 0);
    }
  }

  if (EPI == 2 && tn >= 8) {
    // sigma-permuted V^T store: pair fragments (ip, ip+1) hold tokens (t, t+16)
    const int fbase = (tn - 8) * 128 + wc;
#pragma unroll
    for (int ip = 0; ip < 4; ip += 2) {
      int t0 = tm * 128 + wr + ip * 16 + lq * 4;   // token of reg r=0 (even frag)
      int seg = t0 >> 8;
      int ts  = t0 & 255;
      int c32 = (ts >> 5) * 16 + (ts & 15);        // u32 col for r=0
#pragma unroll
      for (int j = 0; j < 4; ++j) {
        int f = fbase + j * 16 + lr;
        uint32_t* rp = (uint32_t*)&Cv2[((long)(seg * 1024 + f)) * 256];
        uint4 U;
        U.x = pack_bf16(acc[ip][j][0] * scale, acc[ip + 1][j][0] * scale);
        U.y = pack_bf16(acc[ip][j][1] * scale, acc[ip + 1][j][1] * scale);
        U.z = pack_bf16(acc[ip][j][2] * scale, acc[ip + 1][j][2] * scale);
        U.w = pack_bf16(acc[ip][j][3] * scale, acc[ip + 1][j][3] * scale);
        *(uint4*)&rp[c32] = U;
      }
    }
    return;
  }

#pragma unroll
  for (int i = 0; i < 4; ++i) {
    int rg0 = tm * 128 + wr + i * 16 + lq * 4;
#pragma unroll
    for (int j = 0; j < 4; ++j) {
      int cg = tn * 128 + wc + j * 16 + lr;
#pragma unroll
      for (int r = 0; r < 4; ++r) {
        float v = acc[i][j][r] * scale;
        long off = (long)(rg0 + r) * ldc + cg;
        if (EPI == 0) ((float*)Cv)[off] = v;
        else          ((unsigned short*)Cv)[off] = f2bf(v);
      }
    }
  }
}

// ---------------- segment-local dilated attention (wave-independent) ----------
// Block = 4 waves; EACH WAVE owns one 64-query block x all 256 keys of its
// (b,h,s) segment -> per-key max reduces in-wave, w LDS slice is WAVE-PRIVATE,
// and the main loop has ZERO __syncthreads (only one after V staging).
// Keys processed in 8 chunks of 32 (prefetched from global, L2-hot via XCD
// remap). w packed u32 pairs (keys lr, lr+16 of the chunk) -- same sigma as
// vtb's GEMM epilogue. den via ones-MFMA (same bf16 weights as num).
// PV: D[f][q] = mfma(A=V^T frag, B=w frag) -> packed 8B output stores.
__global__ __launch_bounds__(256, 2) void attn_kernel(
    const unsigned short* __restrict__ qb,    // [16384][1024] bf16, q*scale
    const unsigned short* __restrict__ kb,    // [2048][1024] bf16 dilated keys
    const unsigned short* __restrict__ vtb,   // sigma-permuted V^T
    unsigned short* __restrict__ attout)      // [16384][1024] bf16, col = h*64+d
{
  __shared__ unsigned short v_t[64 * 256];    // [f][g] swizzled, 32 KB
  __shared__ uint32_t w32[4][64][18];         // per-wave [q][col] slices, 18.4 KB

  // XCD-grouping remap (bijective): XCD k = blockIdx%8 gets contiguous work.
  const int u = (blockIdx.x & 7) * 128 + (blockIdx.x >> 3);
  const int e8 = u & 7, h = (u >> 3) & 15, s = (u >> 7) & 3, b = u >> 9;
  const int tid = threadIdx.x, w = tid >> 6, lane = tid & 63;
  const int lr = lane & 15, lq = lane >> 4;
  const long qrow0 = (long)b * 8192 + s * 2048 + e8 * 256 + w * 64;  // wave's qblock
  const int hc = h * 64;

  const unsigned short* kbase = kb + ((long)(b * 4 + s) * 256) * 1024 + hc;
  const unsigned short* vbase = vtb + ((long)(b * 4 + s) * 1024 + hc) * 256;

  // ---- stage V^T [64][256] (chunk-XOR swizzled; global order already sigma)
#pragma unroll
  for (int it = 0; it < 8; ++it) {
    int e = (it * 256 + tid) * 8;
    int f = e >> 8;
    int ch = (e >> 3) & 31;
    gload_lds16(vbase + (long)f * 256 + ((ch ^ (f & 7)) * 8), &v_t[e]);
  }

  // ---- Q fragments for this wave's 64 queries (persistent)
  const unsigned short* qbase = qb + qrow0 * 1024 + hc;
  short8 aq[4][2];
#pragma unroll
  for (int i = 0; i < 4; ++i)
#pragma unroll
    for (int kk = 0; kk < 2; ++kk)
      aq[i][kk] = *(const short8*)&qbase[(i * 16 + lr) * 1024 + (kk * 4 + lq) * 8];

  __syncthreads();   // V staged (only barrier in the kernel)

  short8 ones;
#pragma unroll
  for (int e = 0; e < 8; ++e) ones[e] = (short)0x3F80;  // bf16 1.0

  uint32_t (*wsl)[18] = w32[w];                // wave-private w slice

  f32x4 acc_pv[4][4] = {};                     // [qi][ct]
  f32x4 acc_den[4] = {};                       // [qi]

  // K chunk 0 -> registers
  short8 bkc[2][2], bkn[2][2];                 // [j][kk], cur / next
#pragma unroll
  for (int j = 0; j < 2; ++j)
#pragma unroll
    for (int kk = 0; kk < 2; ++kk)
      bkc[j][kk] = *(const short8*)&kbase[(long)(j * 16 + lr) * 1024 + (kk * 4 + lq) * 8];

#pragma unroll
  for (int c = 0; c < 8; ++c) {
    // ---- prefetch next K chunk
    if (c < 7) {
#pragma unroll
      for (int j = 0; j < 2; ++j)
#pragma unroll
        for (int kk = 0; kk < 2; ++kk)
          bkn[j][kk] = *(const short8*)
            &kbase[(long)((c + 1) * 32 + j * 16 + lr) * 1024 + (kk * 4 + lq) * 8];
    }

    // ---- QK^T for 32 keys: acc_s[i][j], D[row=q][col=key]
    f32x4 acc_s[4][2] = {};
#pragma unroll
    for (int kk = 0; kk < 2; ++kk)
#pragma unroll
      for (int i = 0; i < 4; ++i)
#pragma unroll
        for (int j = 0; j < 2; ++j)
          acc_s[i][j] = __builtin_amdgcn_mfma_f32_16x16x32_bf16(aq[i][kk], bkc[j][kk], acc_s[i][j], 0, 0, 0);

    // ---- per-key (column) max over the 64-query block (in-wave)
    float cmax[2];
#pragma unroll
    for (int j = 0; j < 2; ++j) {
      float m = -3.4e38f;
#pragma unroll
      for (int i = 0; i < 4; ++i)
#pragma unroll
        for (int r = 0; r < 4; ++r) m = fmaxf(m, acc_s[i][j][r]);
      m = fmaxf(m, __shfl_xor(m, 16));
      m = fmaxf(m, __shfl_xor(m, 32));
      cmax[j] = m;
    }

    // ---- w = exp(s - cmax): packed u32 (keys lr / lr+16) -> wsl[q][lr]
#pragma unroll
    for (int i = 0; i < 4; ++i) {
#pragma unroll
      for (int r = 0; r < 4; ++r) {
        int q = i * 16 + lq * 4 + r;
        wsl[q][lr] = pack_bf16(__expf(acc_s[i][0][r] - cmax[0]),
                               __expf(acc_s[i][1][r] - cmax[1]));
      }
    }
    // (compiler inserts lgkmcnt wait before the dependent reads below)

    // ---- PV + den for this chunk (k-dim = 32 keys)
    short8 av[4];
#pragma unroll
    for (int ct = 0; ct < 4; ++ct) {
      int frow = ct * 16 + lr;
      av[ct] = *(const short8*)&v_t[frow * 256 + (((c * 4 + lq) ^ (frow & 7)) << 3)];
    }
#pragma unroll
    for (int qi = 0; qi < 4; ++qi) {
      short8 bw = *(const short8*)&wsl[qi * 16 + lr][lq * 4];
      acc_den[qi] = __builtin_amdgcn_mfma_f32_16x16x32_bf16(ones, bw, acc_den[qi], 0, 0, 0);
#pragma unroll
      for (int ct = 0; ct < 4; ++ct)
        acc_pv[qi][ct] = __builtin_amdgcn_mfma_f32_16x16x32_bf16(av[ct], bw, acc_pv[qi][ct], 0, 0, 0);
    }

    // ---- rotate prefetch buffer (register rename after full unroll)
#pragma unroll
    for (int j = 0; j < 2; ++j)
#pragma unroll
      for (int kk = 0; kk < 2; ++kk)
        bkc[j][kk] = bkn[j][kk];
  }

  // ---- epilogue: out[q][f] = num/den, packed 8B stores
#pragma unroll
  for (int qi = 0; qi < 4; ++qi) {
    float inv = 1.0f / (acc_den[qi][0] + 1e-10f);
    long orow = (qrow0 + qi * 16 + lr) * 1024 + hc;
#pragma unroll
    for (int ct = 0; ct < 4; ++ct) {
      ushort4v p;
#pragma unroll
      for (int r = 0; r < 4; ++r) p[r] = f2bf(acc_pv[qi][ct][r] * inv);
      *(ushort4v*)&attout[orow + ct * 16 + lq * 4] = p;
    }
  }
}

extern "C" void kernel_launch(void* const* d_in, const int* in_sizes, int n_in,
                              void* d_out, int out_size, void* d_ws, size_t ws_size,
                              hipStream_t stream) {
  (void)in_sizes; (void)n_in; (void)out_size; (void)ws_size;
  const float* x    = (const float*)d_in[0];
  const float* Wqkv = (const float*)d_in[1];
  const float* Wout = (const float*)d_in[2];
  float* out = (float*)d_out;
  char* ws = (char*)d_ws;

  // workspace layout (80 MB). xb aliases attout: xb is dead before attn writes.
  unsigned short* xb     = (unsigned short*)(ws);               // 33,554,432 B
  unsigned short* attout = (unsigned short*)(ws);               // (same region)
  unsigned short* wqkvb  = (unsigned short*)(ws + 33554432);    //  6,291,456 B
  unsigned short* woutb  = (unsigned short*)(ws + 39845888);    //  2,097,152 B
  unsigned short* qbuf   = (unsigned short*)(ws + 41943040);    // 33,554,432 B
  unsigned short* kbuf   = (unsigned short*)(ws + 75497472);    //  4,194,304 B
  unsigned short* vtb    = (unsigned short*)(ws + 79691776);    //  4,194,304 B

  cvt_kernel<<<16384, 256, 0, stream>>>(x, xb, 16777216);
  cvt_kernel<<<3072, 256, 0, stream>>>(Wqkv, wqkvb, 3 * 1024 * 1024);
  cvt_kernel<<<1024, 256, 0, stream>>>(Wout, woutb, 1024 * 1024);

  // Q = (x @ Wq^T) * hd^-0.5  -> qbuf [16384][1024] bf16
  gemm_bt<1><<<dim3(128, 8), 256, 0, stream>>>(
      xb, wqkvb, (void*)qbuf, nullptr, 0.125f, 1024, 1024, 1024);
  // K,V at dilated rows (every 8th): K -> kbuf [2048][1024], V -> vtb (sigma V^T)
  gemm_bt<2><<<dim3(16, 16), 256, 0, stream>>>(
      xb, wqkvb + 1024 * 1024, (void*)kbuf, vtb, 1.0f, 8192, 1024, 1024);

  attn_kernel<<<1024, 256, 0, stream>>>(qbuf, kbuf, vtb, attout);

  // final projection: out = attout @ Wout^T (f32 output)
  gemm_bt<0><<<dim3(128, 8), 256, 0, stream>>>(
      attout, woutb, (void*)out, nullptr, 1.0f, 1024, 1024, 1024);
}

// Round 7
// 172.109 us; speedup vs baseline: 1.6596x; 1.0697x over previous
//
#include <hip/hip_runtime.h>
#include <hip/hip_bf16.h>
#include <stdint.h>

// Problem constants: B=2, M=8192, D=1024, H=16, hd=64, SEG=2048, DIL=8
// => S=4 segments, Kn=256 dilated keys/segment, nb=32 query blocks of 64.

typedef __attribute__((ext_vector_type(8))) short short8;
typedef __attribute__((ext_vector_type(4))) float f32x4;
typedef __attribute__((ext_vector_type(4))) unsigned short ushort4v;

#define DEVI static __device__ __forceinline__

DEVI unsigned short f2bf(float f) {
  union { float f; uint32_t u; } v; v.f = f;
  return (unsigned short)((v.u + 0x7FFFu + ((v.u >> 16) & 1u)) >> 16);
}

// Pure-C bf16 pair pack (v_cvt_pk_bf16_f32 inline asm was broken - round 4/5).
DEVI uint32_t pack_bf16(float lo, float hi) {
  return (uint32_t)f2bf(lo) | ((uint32_t)f2bf(hi) << 16);
}

DEVI void gload_lds16(const void* g, void* l) {
  __builtin_amdgcn_global_load_lds((const __attribute__((address_space(1))) void*)g,
                                   (__attribute__((address_space(3))) void*)l,
                                   16, 0, 0);
}

// ---------------- f32 -> bf16 convert ----------------
__global__ void cvt_kernel(const float* __restrict__ in, unsigned short* __restrict__ out, int n) {
  int i = (blockIdx.x * 256 + threadIdx.x) * 4;
  if (i >= n) return;
  float4 f = *(const float4*)(in + i);
  uint2 o;
  o.x = (uint32_t)f2bf(f.x) | ((uint32_t)f2bf(f.y) << 16);
  o.y = (uint32_t)f2bf(f.z) | ((uint32_t)f2bf(f.w) << 16);
  *(uint2*)(out + i) = o;
}

// ======== 8-phase 256x256 GEMM (T2-swizzle + T3/T4 counted-vmcnt + T5) ========
// C[m,n] = scale * sum_k A[m,k]*B[n,k];  A [M][1024], B [1024][1024] bf16.
// 512 threads = 8 waves (2M x 4N); per-wave C = 128x64, rows/cols interleaved
// across tile halves so each phase (quadrant a,b) reads exactly one A-half and
// one B-half. 2 K-tile LDS buffers; per phase: 12 ds_read_b128 + stage one
// 128x64 half-unit (2 global_load_lds) + 16 MFMA + vmcnt(4) + s_barrier.
// Staging is just-in-time: phases 0-3 stage the odd K-tile (buf1) consumed in
// phases 4-7; phases 4-7 stage the next even K-tile (buf0). Write-after-read
// separation >= 2 phases (1+ barrier) for every unit (verified). vmcnt never
// drains to 0 in steady state (4-6 loads in flight).
#define STAGE_A(bf, hf, kt) do { \
  gload_lds16(Abase + (long)((hf) * 128 + srow0) * 1024 + (kt) * 64 + scol0, &smA[bf][hf][se0]); \
  gload_lds16(Abase + (long)((hf) * 128 + srow1) * 1024 + (kt) * 64 + scol1, &smA[bf][hf][se1]); \
} while (0)
#define STAGE_B(bf, hf, kt) do { \
  gload_lds16(Bbase + (long)((hf) * 128 + srow0) * 1024 + (kt) * 64 + scol0, &smB[bf][hf][se0]); \
  gload_lds16(Bbase + (long)((hf) * 128 + srow1) * 1024 + (kt) * 64 + scol1, &smB[bf][hf][se1]); \
} while (0)

template<bool OUT_F32>
__global__ __launch_bounds__(512, 2) void gemm8p(
    const unsigned short* __restrict__ A, const unsigned short* __restrict__ B,
    void* __restrict__ Cv, float scale)
{
  __shared__ unsigned short smA[2][2][128 * 64];   // [buf][half][r][k] swizzled
  __shared__ unsigned short smB[2][2][128 * 64];
  const int tid = threadIdx.x;
  const int tm = blockIdx.x, tn = blockIdx.y;
  const int w = tid >> 6, lane = tid & 63;
  const int wm = w >> 2, wn = w & 3;
  const int lr = lane & 15, lq = lane >> 4;

  // staging source precompute (2 x 16B per thread per 128x64 unit)
  const int e0 = tid * 8,        e1 = (512 + tid) * 8;
  const int srow0 = e0 >> 6,     srow1 = e1 >> 6;
  const int sc0 = (e0 >> 3) & 7, sc1 = (e1 >> 3) & 7;
  const int scol0 = (sc0 ^ (srow0 & 7)) * 8, scol1 = (sc1 ^ (srow1 & 7)) * 8;
  const int se0 = e0, se1 = e1;

  const unsigned short* Abase = A + (long)tm * 256 * 1024;
  const unsigned short* Bbase = B + (long)tn * 256 * 1024;

  f32x4 acc[8][4] = {};

  // prologue: all 4 units of kt=0 into buf0; wait oldest 2 units (A0,B0)
  STAGE_A(0, 0, 0); STAGE_B(0, 0, 0); STAGE_A(0, 1, 0); STAGE_B(0, 1, 0);
  asm volatile("s_waitcnt vmcnt(4)" ::: "memory");
  __builtin_amdgcn_s_barrier();
  asm volatile("" ::: "memory");

  for (int t = 0; t < 8; ++t) {
#pragma unroll
    for (int p = 0; p < 8; ++p) {
      const int o = p >> 2;            // 0: kt=2t (buf0), 1: kt=2t+1 (buf1)
      const int a = p & 1;             // A-half of this quadrant
      const int b = (p >> 1) & 1;      // B-half

      // ---- ds_read fragments (12 x b128)
      short8 af[4][2], bfr[2][2];
#pragma unroll
      for (int mi2 = 0; mi2 < 4; ++mi2) {
        int r = wm * 64 + mi2 * 16 + lr;
#pragma unroll
        for (int kk = 0; kk < 2; ++kk) {
          int kc = kk * 4 + lq;
          af[mi2][kk] = *(const short8*)&smA[o][a][r * 64 + ((kc ^ (r & 7)) * 8)];
        }
      }
#pragma unroll
      for (int nj2 = 0; nj2 < 2; ++nj2) {
        int r = wn * 32 + nj2 * 16 + lr;
#pragma unroll
        for (int kk = 0; kk < 2; ++kk) {
          int kc = kk * 4 + lq;
          bfr[nj2][kk] = *(const short8*)&smB[o][b][r * 64 + ((kc ^ (r & 7)) * 8)];
        }
      }

      // ---- stage one half-unit (just-in-time schedule)
      switch (p) {
        case 0: STAGE_A(1, 0, 2 * t + 1); break;
        case 1: STAGE_B(1, 0, 2 * t + 1); break;
        case 2: STAGE_A(1, 1, 2 * t + 1); break;
        case 3: STAGE_B(1, 1, 2 * t + 1); break;
        case 4: if (t < 7) STAGE_A(0, 0, 2 * t + 2); break;
        case 5: if (t < 7) STAGE_B(0, 0, 2 * t + 2); break;
        case 6: if (t < 7) STAGE_A(0, 1, 2 * t + 2); break;
        case 7: if (t < 7) STAGE_B(0, 1, 2 * t + 2); break;
      }

      // ---- MFMA cluster (16)
      __builtin_amdgcn_s_setprio(1);
#pragma unroll
      for (int kk = 0; kk < 2; ++kk)
#pragma unroll
        for (int mi2 = 0; mi2 < 4; ++mi2)
#pragma unroll
          for (int nj2 = 0; nj2 < 2; ++nj2)
            acc[a * 4 + mi2][b * 2 + nj2] = __builtin_amdgcn_mfma_f32_16x16x32_bf16(
                af[mi2][kk], bfr[nj2][kk], acc[a * 4 + mi2][b * 2 + nj2], 0, 0, 0);
      __builtin_amdgcn_s_setprio(0);

      // ---- counted wait + barrier (tightened in last iteration: no refill)
      if (t < 7) {
        asm volatile("s_waitcnt vmcnt(4)" ::: "memory");
      } else {
        if (p < 4)       asm volatile("s_waitcnt vmcnt(4)" ::: "memory");
        else if (p == 4) asm volatile("s_waitcnt vmcnt(2)" ::: "memory");
        else             asm volatile("s_waitcnt vmcnt(0)" ::: "memory");
      }
      __builtin_amdgcn_s_barrier();
      asm volatile("" ::: "memory");
    }
  }

  // ---- epilogue
  const int row0 = tm * 256 + wm * 64 + lq * 4;
  const int col0 = tn * 256 + wn * 32 + lr;
#pragma unroll
  for (int mi = 0; mi < 8; ++mi) {
    int row = row0 + (mi & 3) * 16 + (mi >> 2) * 128;
#pragma unroll
    for (int nj = 0; nj < 4; ++nj) {
      int col = col0 + (nj & 1) * 16 + (nj >> 1) * 128;
#pragma unroll
      for (int rr = 0; rr < 4; ++rr) {
        float v = acc[mi][nj][rr] * scale;
        long off = (long)(row + rr) * 1024 + col;
        if (OUT_F32) ((float*)Cv)[off] = v;
        else         ((unsigned short*)Cv)[off] = f2bf(v);
      }
    }
  }
}

// ---------------- 128^2 GEMM, kept for the KV split ----------------
// EPI 2: tn<8 -> bf16 K rows to Cv; tn>=8 -> V TRANSPOSED + sigma-permuted to
// Cv2 (row = seg*1024+f; u32 col c packs tokens (32*(c>>4)+(c&15), +16)).
template<int EPI>
__global__ __launch_bounds__(256, 2) void gemm_bt(
    const unsigned short* __restrict__ A, const unsigned short* __restrict__ B,
    void* __restrict__ Cv, unsigned short* __restrict__ Cv2,
    float scale, long a_row_stride, int ldc, int K)
{
  __shared__ unsigned short smA[128 * 64];
  __shared__ unsigned short smB[128 * 64];
  const int tid = threadIdx.x;
  const int tm = blockIdx.x, tn = blockIdx.y;
  const int w = tid >> 6, lane = tid & 63;
  const int wr = (w >> 1) * 64, wc = (w & 1) * 64;
  const int lr = lane & 15, lq = lane >> 4;

  int se[4], srow[4], scol[4];
#pragma unroll
  for (int i = 0; i < 4; ++i) {
    int e = (i * 256 + tid) * 8;
    int r = e >> 6;
    int cc = (e >> 3) & 7;
    se[i] = e; srow[i] = r; scol[i] = (cc ^ (r & 7)) * 8;
  }

  f32x4 acc[4][4] = {};

  for (int kt = 0; kt < K / 64; ++kt) {
    if (kt) __syncthreads();
#pragma unroll
    for (int i = 0; i < 4; ++i)
      gload_lds16(A + (long)(tm * 128 + srow[i]) * a_row_stride + kt * 64 + scol[i], &smA[se[i]]);
#pragma unroll
    for (int i = 0; i < 4; ++i)
      gload_lds16(B + (long)(tn * 128 + srow[i]) * K + kt * 64 + scol[i], &smB[se[i]]);
    __syncthreads();

#pragma unroll
    for (int kk = 0; kk < 2; ++kk) {
      int kc = kk * 4 + lq;
      short8 af[4], bfm[4];
#pragma unroll
      for (int i = 0; i < 4; ++i) {
        int row = wr + i * 16 + lr;
        af[i] = *(const short8*)&smA[row * 64 + ((kc ^ (row & 7)) * 8)];
      }
#pragma unroll
      for (int j = 0; j < 4; ++j) {
        int row = wc + j * 16 + lr;
        bfm[j] = *(const short8*)&smB[row * 64 + ((kc ^ (row & 7)) * 8)];
      }
#pragma unroll
      for (int i = 0; i < 4; ++i)
#pragma unroll
        for (int j = 0; j < 4; ++j)
          acc[i][j] = __builtin_amdgcn_mfma_f32_16x16x32_bf16(af[i], bfm[j], acc[i][j], 0, 0, 0);
    }
  }

  if (EPI == 2 && tn >= 8) {
    const int fbase = (tn - 8) * 128 + wc;
#pragma unroll
    for (int ip = 0; ip < 4; ip += 2) {
      int t0 = tm * 128 + wr + ip * 16 + lq * 4;
      int seg = t0 >> 8;
      int ts  = t0 & 255;
      int c32 = (ts >> 5) * 16 + (ts & 15);
#pragma unroll
      for (int j = 0; j < 4; ++j) {
        int f = fbase + j * 16 + lr;
        uint32_t* rp = (uint32_t*)&Cv2[((long)(seg * 1024 + f)) * 256];
        uint4 U;
        U.x = pack_bf16(acc[ip][j][0] * scale, acc[ip + 1][j][0] * scale);
        U.y = pack_bf16(acc[ip][j][1] * scale, acc[ip + 1][j][1] * scale);
        U.z = pack_bf16(acc[ip][j][2] * scale, acc[ip + 1][j][2] * scale);
        U.w = pack_bf16(acc[ip][j][3] * scale, acc[ip + 1][j][3] * scale);
        *(uint4*)&rp[c32] = U;
      }
    }
    return;
  }

#pragma unroll
  for (int i = 0; i < 4; ++i) {
    int rg0 = tm * 128 + wr + i * 16 + lq * 4;
#pragma unroll
    for (int j = 0; j < 4; ++j) {
      int cg = tn * 128 + wc + j * 16 + lr;
#pragma unroll
      for (int r = 0; r < 4; ++r) {
        float v = acc[i][j][r] * scale;
        long off = (long)(rg0 + r) * ldc + cg;
        if (EPI == 0) ((float*)Cv)[off] = v;
        else          ((unsigned short*)Cv)[off] = f2bf(v);
      }
    }
  }
}

// ---------------- segment-local dilated attention (wave-independent) ----------
__global__ __launch_bounds__(256, 2) void attn_kernel(
    const unsigned short* __restrict__ qb,    // [16384][1024] bf16, q*scale
    const unsigned short* __restrict__ kb,    // [2048][1024] bf16 dilated keys
    const unsigned short* __restrict__ vtb,   // sigma-permuted V^T
    unsigned short* __restrict__ attout)      // [16384][1024] bf16, col = h*64+d
{
  __shared__ unsigned short v_t[64 * 256];    // [f][g] swizzled, 32 KB
  __shared__ uint32_t w32[4][64][18];         // per-wave [q][col] slices, 18.4 KB

  const int u = (blockIdx.x & 7) * 128 + (blockIdx.x >> 3);
  const int e8 = u & 7, h = (u >> 3) & 15, s = (u >> 7) & 3, b = u >> 9;
  const int tid = threadIdx.x, w = tid >> 6, lane = tid & 63;
  const int lr = lane & 15, lq = lane >> 4;
  const long qrow0 = (long)b * 8192 + s * 2048 + e8 * 256 + w * 64;
  const int hc = h * 64;

  const unsigned short* kbase = kb + ((long)(b * 4 + s) * 256) * 1024 + hc;
  const unsigned short* vbase = vtb + ((long)(b * 4 + s) * 1024 + hc) * 256;

#pragma unroll
  for (int it = 0; it < 8; ++it) {
    int e = (it * 256 + tid) * 8;
    int f = e >> 8;
    int ch = (e >> 3) & 31;
    gload_lds16(vbase + (long)f * 256 + ((ch ^ (f & 7)) * 8), &v_t[e]);
  }

  const unsigned short* qbase = qb + qrow0 * 1024 + hc;
  short8 aq[4][2];
#pragma unroll
  for (int i = 0; i < 4; ++i)
#pragma unroll
    for (int kk = 0; kk < 2; ++kk)
      aq[i][kk] = *(const short8*)&qbase[(i * 16 + lr) * 1024 + (kk * 4 + lq) * 8];

  __syncthreads();   // V staged (only barrier in the kernel)

  short8 ones;
#pragma unroll
  for (int e = 0; e < 8; ++e) ones[e] = (short)0x3F80;  // bf16 1.0

  uint32_t (*wsl)[18] = w32[w];

  f32x4 acc_pv[4][4] = {};
  f32x4 acc_den[4] = {};

  short8 bkc[2][2], bkn[2][2];
#pragma unroll
  for (int j = 0; j < 2; ++j)
#pragma unroll
    for (int kk = 0; kk < 2; ++kk)
      bkc[j][kk] = *(const short8*)&kbase[(long)(j * 16 + lr) * 1024 + (kk * 4 + lq) * 8];

#pragma unroll
  for (int c = 0; c < 8; ++c) {
    if (c < 7) {
#pragma unroll
      for (int j = 0; j < 2; ++j)
#pragma unroll
        for (int kk = 0; kk < 2; ++kk)
          bkn[j][kk] = *(const short8*)
            &kbase[(long)((c + 1) * 32 + j * 16 + lr) * 1024 + (kk * 4 + lq) * 8];
    }

    f32x4 acc_s[4][2] = {};
#pragma unroll
    for (int kk = 0; kk < 2; ++kk)
#pragma unroll
      for (int i = 0; i < 4; ++i)
#pragma unroll
        for (int j = 0; j < 2; ++j)
          acc_s[i][j] = __builtin_amdgcn_mfma_f32_16x16x32_bf16(aq[i][kk], bkc[j][kk], acc_s[i][j], 0, 0, 0);

    float cmax[2];
#pragma unroll
    for (int j = 0; j < 2; ++j) {
      float m = -3.4e38f;
#pragma unroll
      for (int i = 0; i < 4; ++i)
#pragma unroll
        for (int r = 0; r < 4; ++r) m = fmaxf(m, acc_s[i][j][r]);
      m = fmaxf(m, __shfl_xor(m, 16));
      m = fmaxf(m, __shfl_xor(m, 32));
      cmax[j] = m;
    }

#pragma unroll
    for (int i = 0; i < 4; ++i) {
#pragma unroll
      for (int r = 0; r < 4; ++r) {
        int q = i * 16 + lq * 4 + r;
        wsl[q][lr] = pack_bf16(__expf(acc_s[i][0][r] - cmax[0]),
                               __expf(acc_s[i][1][r] - cmax[1]));
      }
    }

    short8 av[4];
#pragma unroll
    for (int ct = 0; ct < 4; ++ct) {
      int frow = ct * 16 + lr;
      av[ct] = *(const short8*)&v_t[frow * 256 + (((c * 4 + lq) ^ (frow & 7)) << 3)];
    }
#pragma unroll
    for (int qi = 0; qi < 4; ++qi) {
      short8 bw = *(const short8*)&wsl[qi * 16 + lr][lq * 4];
      acc_den[qi] = __builtin_amdgcn_mfma_f32_16x16x32_bf16(ones, bw, acc_den[qi], 0, 0, 0);
#pragma unroll
      for (int ct = 0; ct < 4; ++ct)
        acc_pv[qi][ct] = __builtin_amdgcn_mfma_f32_16x16x32_bf16(av[ct], bw, acc_pv[qi][ct], 0, 0, 0);
    }

#pragma unroll
    for (int j = 0; j < 2; ++j)
#pragma unroll
      for (int kk = 0; kk < 2; ++kk)
        bkc[j][kk] = bkn[j][kk];
  }

#pragma unroll
  for (int qi = 0; qi < 4; ++qi) {
    float inv = 1.0f / (acc_den[qi][0] + 1e-10f);
    long orow = (qrow0 + qi * 16 + lr) * 1024 + hc;
#pragma unroll
    for (int ct = 0; ct < 4; ++ct) {
      ushort4v p;
#pragma unroll
      for (int r = 0; r < 4; ++r) p[r] = f2bf(acc_pv[qi][ct][r] * inv);
      *(ushort4v*)&attout[orow + ct * 16 + lq * 4] = p;
    }
  }
}

extern "C" void kernel_launch(void* const* d_in, const int* in_sizes, int n_in,
                              void* d_out, int out_size, void* d_ws, size_t ws_size,
                              hipStream_t stream) {
  (void)in_sizes; (void)n_in; (void)out_size; (void)ws_size;
  const float* x    = (const float*)d_in[0];
  const float* Wqkv = (const float*)d_in[1];
  const float* Wout = (const float*)d_in[2];
  float* out = (float*)d_out;
  char* ws = (char*)d_ws;

  // workspace layout (80 MB). xb aliases attout: xb is dead before attn writes.
  unsigned short* xb     = (unsigned short*)(ws);               // 33,554,432 B
  unsigned short* attout = (unsigned short*)(ws);               // (same region)
  unsigned short* wqkvb  = (unsigned short*)(ws + 33554432);    //  6,291,456 B
  unsigned short* woutb  = (unsigned short*)(ws + 39845888);    //  2,097,152 B
  unsigned short* qbuf   = (unsigned short*)(ws + 41943040);    // 33,554,432 B
  unsigned short* kbuf   = (unsigned short*)(ws + 75497472);    //  4,194,304 B
  unsigned short* vtb    = (unsigned short*)(ws + 79691776);    //  4,194,304 B

  cvt_kernel<<<16384, 256, 0, stream>>>(x, xb, 16777216);
  cvt_kernel<<<3072, 256, 0, stream>>>(Wqkv, wqkvb, 3 * 1024 * 1024);
  cvt_kernel<<<1024, 256, 0, stream>>>(Wout, woutb, 1024 * 1024);

  // Q = (x @ Wq^T) * hd^-0.5  -> qbuf [16384][1024] bf16  (8-phase 256^2)
  gemm8p<false><<<dim3(64, 4), 512, 0, stream>>>(xb, wqkvb, (void*)qbuf, 0.125f);
  // K,V at dilated rows (every 8th): K -> kbuf [2048][1024], V -> vtb (sigma V^T)
  gemm_bt<2><<<dim3(16, 16), 256, 0, stream>>>(
      xb, wqkvb + 1024 * 1024, (void*)kbuf, vtb, 1.0f, 8192, 1024, 1024);

  attn_kernel<<<1024, 256, 0, stream>>>(qbuf, kbuf, vtb, attout);

  // final projection: out = attout @ Wout^T (f32 output, 8-phase 256^2)
  gemm8p<true><<<dim3(64, 4), 512, 0, stream>>>(attout, woutb, (void*)out, 1.0f);
}

// Round 8
// 164.606 us; speedup vs baseline: 1.7352x; 1.0456x over previous
//
#include <hip/hip_runtime.h>
#include <hip/hip_bf16.h>
#include <stdint.h>

// Problem constants: B=2, M=8192, D=1024, H=16, hd=64, SEG=2048, DIL=8
// => S=4 segments, Kn=256 dilated keys/segment, nb=32 query blocks of 64.

typedef __attribute__((ext_vector_type(8))) short short8;
typedef __attribute__((ext_vector_type(4))) float f32x4;
typedef __attribute__((ext_vector_type(4))) unsigned short ushort4v;

#define DEVI static __device__ __forceinline__

DEVI unsigned short f2bf(float f) {
  union { float f; uint32_t u; } v; v.f = f;
  return (unsigned short)((v.u + 0x7FFFu + ((v.u >> 16) & 1u)) >> 16);
}

// Pure-C bf16 pair pack (v_cvt_pk_bf16_f32 inline asm was broken - round 4/5).
DEVI uint32_t pack_bf16(float lo, float hi) {
  return (uint32_t)f2bf(lo) | ((uint32_t)f2bf(hi) << 16);
}

DEVI void gload_lds16(const void* g, void* l) {
  __builtin_amdgcn_global_load_lds((const __attribute__((address_space(1))) void*)g,
                                   (__attribute__((address_space(3))) void*)l,
                                   16, 0, 0);
}

// ---------------- f32 -> bf16 convert ----------------
__global__ void cvt_kernel(const float* __restrict__ in, unsigned short* __restrict__ out, int n) {
  int i = (blockIdx.x * 256 + threadIdx.x) * 4;
  if (i >= n) return;
  float4 f = *(const float4*)(in + i);
  uint2 o;
  o.x = (uint32_t)f2bf(f.x) | ((uint32_t)f2bf(f.y) << 16);
  o.y = (uint32_t)f2bf(f.z) | ((uint32_t)f2bf(f.w) << 16);
  *(uint2*)(out + i) = o;
}

// ======== 8-phase 256x256 GEMM, gray-code fragment reuse ========
// C[m,n] = scale * sum_k A[m,k]*B[n,k];  A [M][1024], B [1024][1024] bf16.
// 512 threads = 8 waves (2M x 4N); per-wave C = 128x64, rows/cols interleaved
// across tile halves. Phase quadrant order is GRAY CODE (a,b):
// (0,0)->(0,1)->(1,1)->(1,0), so A-frags reload only on q=0,2 (8 reads) and
// B-frags on q=0,1,3 (4 reads): 56 ds_read_b128/iter vs 96 naive -- LDS-read
// time (~672 cyc/CU/phase) now matches MFMA time (~621). m201 barrier rhythm:
// {ds_read; stage; barrier; lgkm0; MFMA16; vmcnt(4); barrier}. Stage order is
// consumption order (A0,B0,B1,A1), lag >=3 phases => uniform vmcnt(4) is safe
// (allows only the last 2 phases' 4 loads pending). Tail drains 4/2/0.
#define STAGE_A(bf, hf, kt) do { \
  gload_lds16(Abase + (long)((hf) * 128 + srow0) * 1024 + (kt) * 64 + scol0, &smA[bf][hf][se0]); \
  gload_lds16(Abase + (long)((hf) * 128 + srow1) * 1024 + (kt) * 64 + scol1, &smA[bf][hf][se1]); \
} while (0)
#define STAGE_B(bf, hf, kt) do { \
  gload_lds16(Bbase + (long)((hf) * 128 + srow0) * 1024 + (kt) * 64 + scol0, &smB[bf][hf][se0]); \
  gload_lds16(Bbase + (long)((hf) * 128 + srow1) * 1024 + (kt) * 64 + scol1, &smB[bf][hf][se1]); \
} while (0)

template<bool OUT_F32>
__global__ __launch_bounds__(512, 1) void gemm8p(
    const unsigned short* __restrict__ A, const unsigned short* __restrict__ B,
    void* __restrict__ Cv, float scale)
{
  __shared__ unsigned short smA[2][2][128 * 64];   // [buf][half][r][k] swizzled
  __shared__ unsigned short smB[2][2][128 * 64];
  const int tid = threadIdx.x;
  const int tm = blockIdx.x, tn = blockIdx.y;
  const int w = tid >> 6, lane = tid & 63;
  const int wm = w >> 2, wn = w & 3;
  const int lr = lane & 15, lq = lane >> 4;

  // staging source precompute (2 x 16B per thread per 128x64 unit)
  const int e0 = tid * 8,        e1 = (512 + tid) * 8;
  const int srow0 = e0 >> 6,     srow1 = e1 >> 6;
  const int sc0 = (e0 >> 3) & 7, sc1 = (e1 >> 3) & 7;
  const int scol0 = (sc0 ^ (srow0 & 7)) * 8, scol1 = (sc1 ^ (srow1 & 7)) * 8;
  const int se0 = e0, se1 = e1;

  const unsigned short* Abase = A + (long)tm * 256 * 1024;
  const unsigned short* Bbase = B + (long)tn * 256 * 1024;

  f32x4 acc[8][4] = {};
  short8 af[4][2];   // current A-half fragments (persist across phases)
  short8 bfr[2][2];  // current B-half fragments

  // prologue: all 4 units of kt=0 into buf0, consumption order A0,B0,B1,A1
  STAGE_A(0, 0, 0); STAGE_B(0, 0, 0); STAGE_B(0, 1, 0); STAGE_A(0, 1, 0);
  asm volatile("s_waitcnt vmcnt(4)" ::: "memory");
  __builtin_amdgcn_s_barrier();
  asm volatile("" ::: "memory");

  for (int t = 0; t < 8; ++t) {
#pragma unroll
    for (int p = 0; p < 8; ++p) {
      const int o = p >> 2;            // 0: kt=2t (buf0), 1: kt=2t+1 (buf1)
      const int q = p & 3;
      const int a = q >> 1;            // A-half: 0,0,1,1
      const int b = (q >> 1) ^ (q & 1);// B-half: 0,1,1,0 (gray)

      // ---- ds_read only NEW fragments
      if ((q & 1) == 0) {              // q=0,2: new A-half (8 x b128)
#pragma unroll
        for (int mi2 = 0; mi2 < 4; ++mi2) {
          int r = wm * 64 + mi2 * 16 + lr;
#pragma unroll
          for (int kk = 0; kk < 2; ++kk) {
            int kc = kk * 4 + lq;
            af[mi2][kk] = *(const short8*)&smA[o][a][r * 64 + ((kc ^ (r & 7)) * 8)];
          }
        }
      }
      if (q != 2) {                    // q=0,1,3: new B-half (4 x b128)
#pragma unroll
        for (int nj2 = 0; nj2 < 2; ++nj2) {
          int r = wn * 32 + nj2 * 16 + lr;
#pragma unroll
          for (int kk = 0; kk < 2; ++kk) {
            int kc = kk * 4 + lq;
            bfr[nj2][kk] = *(const short8*)&smB[o][b][r * 64 + ((kc ^ (r & 7)) * 8)];
          }
        }
      }

      // ---- stage one half-unit (consumption order, lag >= 3 phases)
      switch (p) {
        case 0: STAGE_A(1, 0, 2 * t + 1); break;
        case 1: STAGE_B(1, 0, 2 * t + 1); break;
        case 2: STAGE_B(1, 1, 2 * t + 1); break;
        case 3: STAGE_A(1, 1, 2 * t + 1); break;
        case 4: if (t < 7) STAGE_A(0, 0, 2 * t + 2); break;
        case 5: if (t < 7) STAGE_B(0, 0, 2 * t + 2); break;
        case 6: if (t < 7) STAGE_B(0, 1, 2 * t + 2); break;
        case 7: if (t < 7) STAGE_A(0, 1, 2 * t + 2); break;
      }

      // ---- barrier, then drain LDS reads, then MFMA cluster
      __builtin_amdgcn_s_barrier();
      asm volatile("s_waitcnt lgkmcnt(0)" ::: "memory");
      __builtin_amdgcn_sched_barrier(0);

      __builtin_amdgcn_s_setprio(1);
#pragma unroll
      for (int kk = 0; kk < 2; ++kk)
#pragma unroll
        for (int mi2 = 0; mi2 < 4; ++mi2)
#pragma unroll
          for (int nj2 = 0; nj2 < 2; ++nj2)
            acc[a * 4 + mi2][b * 2 + nj2] = __builtin_amdgcn_mfma_f32_16x16x32_bf16(
                af[mi2][kk], bfr[nj2][kk], acc[a * 4 + mi2][b * 2 + nj2], 0, 0, 0);
      __builtin_amdgcn_s_setprio(0);

      // ---- counted wait + barrier (tail drains 4/2/0 on last iteration)
      if (t < 7 || p < 4) {
        asm volatile("s_waitcnt vmcnt(4)" ::: "memory");
      } else if (p == 4) {
        asm volatile("s_waitcnt vmcnt(2)" ::: "memory");
      } else {
        asm volatile("s_waitcnt vmcnt(0)" ::: "memory");
      }
      __builtin_amdgcn_s_barrier();
      asm volatile("" ::: "memory");
    }
  }

  // ---- epilogue
  const int row0 = tm * 256 + wm * 64 + lq * 4;
  const int col0 = tn * 256 + wn * 32 + lr;
#pragma unroll
  for (int mi = 0; mi < 8; ++mi) {
    int row = row0 + (mi & 3) * 16 + (mi >> 2) * 128;
#pragma unroll
    for (int nj = 0; nj < 4; ++nj) {
      int col = col0 + (nj & 1) * 16 + (nj >> 1) * 128;
#pragma unroll
      for (int rr = 0; rr < 4; ++rr) {
        float v = acc[mi][nj][rr] * scale;
        long off = (long)(row + rr) * 1024 + col;
        if (OUT_F32) ((float*)Cv)[off] = v;
        else         ((unsigned short*)Cv)[off] = f2bf(v);
      }
    }
  }
}

// ---------------- 128^2 GEMM, kept for the KV split ----------------
// EPI 2: tn<8 -> bf16 K rows to Cv; tn>=8 -> V TRANSPOSED + sigma-permuted to
// Cv2 (row = seg*1024+f; u32 col c packs tokens (32*(c>>4)+(c&15), +16)).
template<int EPI>
__global__ __launch_bounds__(256, 2) void gemm_bt(
    const unsigned short* __restrict__ A, const unsigned short* __restrict__ B,
    void* __restrict__ Cv, unsigned short* __restrict__ Cv2,
    float scale, long a_row_stride, int ldc, int K)
{
  __shared__ unsigned short smA[128 * 64];
  __shared__ unsigned short smB[128 * 64];
  const int tid = threadIdx.x;
  const int tm = blockIdx.x, tn = blockIdx.y;
  const int w = tid >> 6, lane = tid & 63;
  const int wr = (w >> 1) * 64, wc = (w & 1) * 64;
  const int lr = lane & 15, lq = lane >> 4;

  int se[4], srow[4], scol[4];
#pragma unroll
  for (int i = 0; i < 4; ++i) {
    int e = (i * 256 + tid) * 8;
    int r = e >> 6;
    int cc = (e >> 3) & 7;
    se[i] = e; srow[i] = r; scol[i] = (cc ^ (r & 7)) * 8;
  }

  f32x4 acc[4][4] = {};

  for (int kt = 0; kt < K / 64; ++kt) {
    if (kt) __syncthreads();
#pragma unroll
    for (int i = 0; i < 4; ++i)
      gload_lds16(A + (long)(tm * 128 + srow[i]) * a_row_stride + kt * 64 + scol[i], &smA[se[i]]);
#pragma unroll
    for (int i = 0; i < 4; ++i)
      gload_lds16(B + (long)(tn * 128 + srow[i]) * K + kt * 64 + scol[i], &smB[se[i]]);
    __syncthreads();

#pragma unroll
    for (int kk = 0; kk < 2; ++kk) {
      int kc = kk * 4 + lq;
      short8 af[4], bfm[4];
#pragma unroll
      for (int i = 0; i < 4; ++i) {
        int row = wr + i * 16 + lr;
        af[i] = *(const short8*)&smA[row * 64 + ((kc ^ (row & 7)) * 8)];
      }
#pragma unroll
      for (int j = 0; j < 4; ++j) {
        int row = wc + j * 16 + lr;
        bfm[j] = *(const short8*)&smB[row * 64 + ((kc ^ (row & 7)) * 8)];
      }
#pragma unroll
      for (int i = 0; i < 4; ++i)
#pragma unroll
        for (int j = 0; j < 4; ++j)
          acc[i][j] = __builtin_amdgcn_mfma_f32_16x16x32_bf16(af[i], bfm[j], acc[i][j], 0, 0, 0);
    }
  }

  if (EPI == 2 && tn >= 8) {
    const int fbase = (tn - 8) * 128 + wc;
#pragma unroll
    for (int ip = 0; ip < 4; ip += 2) {
      int t0 = tm * 128 + wr + ip * 16 + lq * 4;
      int seg = t0 >> 8;
      int ts  = t0 & 255;
      int c32 = (ts >> 5) * 16 + (ts & 15);
#pragma unroll
      for (int j = 0; j < 4; ++j) {
        int f = fbase + j * 16 + lr;
        uint32_t* rp = (uint32_t*)&Cv2[((long)(seg * 1024 + f)) * 256];
        uint4 U;
        U.x = pack_bf16(acc[ip][j][0] * scale, acc[ip + 1][j][0] * scale);
        U.y = pack_bf16(acc[ip][j][1] * scale, acc[ip + 1][j][1] * scale);
        U.z = pack_bf16(acc[ip][j][2] * scale, acc[ip + 1][j][2] * scale);
        U.w = pack_bf16(acc[ip][j][3] * scale, acc[ip + 1][j][3] * scale);
        *(uint4*)&rp[c32] = U;
      }
    }
    return;
  }

#pragma unroll
  for (int i = 0; i < 4; ++i) {
    int rg0 = tm * 128 + wr + i * 16 + lq * 4;
#pragma unroll
    for (int j = 0; j < 4; ++j) {
      int cg = tn * 128 + wc + j * 16 + lr;
#pragma unroll
      for (int r = 0; r < 4; ++r) {
        float v = acc[i][j][r] * scale;
        long off = (long)(rg0 + r) * ldc + cg;
        if (EPI == 0) ((float*)Cv)[off] = v;
        else          ((unsigned short*)Cv)[off] = f2bf(v);
      }
    }
  }
}

// ---------------- segment-local dilated attention (wave-independent) ----------
__global__ __launch_bounds__(256, 2) void attn_kernel(
    const unsigned short* __restrict__ qb,    // [16384][1024] bf16, q*scale
    const unsigned short* __restrict__ kb,    // [2048][1024] bf16 dilated keys
    const unsigned short* __restrict__ vtb,   // sigma-permuted V^T
    unsigned short* __restrict__ attout)      // [16384][1024] bf16, col = h*64+d
{
  __shared__ unsigned short v_t[64 * 256];    // [f][g] swizzled, 32 KB
  __shared__ uint32_t w32[4][64][18];         // per-wave [q][col] slices, 18.4 KB

  const int u = (blockIdx.x & 7) * 128 + (blockIdx.x >> 3);
  const int e8 = u & 7, h = (u >> 3) & 15, s = (u >> 7) & 3, b = u >> 9;
  const int tid = threadIdx.x, w = tid >> 6, lane = tid & 63;
  const int lr = lane & 15, lq = lane >> 4;
  const long qrow0 = (long)b * 8192 + s * 2048 + e8 * 256 + w * 64;
  const int hc = h * 64;

  const unsigned short* kbase = kb + ((long)(b * 4 + s) * 256) * 1024 + hc;
  const unsigned short* vbase = vtb + ((long)(b * 4 + s) * 1024 + hc) * 256;

#pragma unroll
  for (int it = 0; it < 8; ++it) {
    int e = (it * 256 + tid) * 8;
    int f = e >> 8;
    int ch = (e >> 3) & 31;
    gload_lds16(vbase + (long)f * 256 + ((ch ^ (f & 7)) * 8), &v_t[e]);
  }

  const unsigned short* qbase = qb + qrow0 * 1024 + hc;
  short8 aq[4][2];
#pragma unroll
  for (int i = 0; i < 4; ++i)
#pragma unroll
    for (int kk = 0; kk < 2; ++kk)
      aq[i][kk] = *(const short8*)&qbase[(i * 16 + lr) * 1024 + (kk * 4 + lq) * 8];

  __syncthreads();   // V staged (only barrier in the kernel)

  short8 ones;
#pragma unroll
  for (int e = 0; e < 8; ++e) ones[e] = (short)0x3F80;  // bf16 1.0

  uint32_t (*wsl)[18] = w32[w];

  f32x4 acc_pv[4][4] = {};
  f32x4 acc_den[4] = {};

  short8 bkc[2][2], bkn[2][2];
#pragma unroll
  for (int j = 0; j < 2; ++j)
#pragma unroll
    for (int kk = 0; kk < 2; ++kk)
      bkc[j][kk] = *(const short8*)&kbase[(long)(j * 16 + lr) * 1024 + (kk * 4 + lq) * 8];

#pragma unroll
  for (int c = 0; c < 8; ++c) {
    if (c < 7) {
#pragma unroll
      for (int j = 0; j < 2; ++j)
#pragma unroll
        for (int kk = 0; kk < 2; ++kk)
          bkn[j][kk] = *(const short8*)
            &kbase[(long)((c + 1) * 32 + j * 16 + lr) * 1024 + (kk * 4 + lq) * 8];
    }

    f32x4 acc_s[4][2] = {};
#pragma unroll
    for (int kk = 0; kk < 2; ++kk)
#pragma unroll
      for (int i = 0; i < 4; ++i)
#pragma unroll
        for (int j = 0; j < 2; ++j)
          acc_s[i][j] = __builtin_amdgcn_mfma_f32_16x16x32_bf16(aq[i][kk], bkc[j][kk], acc_s[i][j], 0, 0, 0);

    float cmax[2];
#pragma unroll
    for (int j = 0; j < 2; ++j) {
      float m = -3.4e38f;
#pragma unroll
      for (int i = 0; i < 4; ++i)
#pragma unroll
        for (int r = 0; r < 4; ++r) m = fmaxf(m, acc_s[i][j][r]);
      m = fmaxf(m, __shfl_xor(m, 16));
      m = fmaxf(m, __shfl_xor(m, 32));
      cmax[j] = m;
    }

#pragma unroll
    for (int i = 0; i < 4; ++i) {
#pragma unroll
      for (int r = 0; r < 4; ++r) {
        int q = i * 16 + lq * 4 + r;
        wsl[q][lr] = pack_bf16(__expf(acc_s[i][0][r] - cmax[0]),
                               __expf(acc_s[i][1][r] - cmax[1]));
      }
    }

    short8 av[4];
#pragma unroll
    for (int ct = 0; ct < 4; ++ct) {
      int frow = ct * 16 + lr;
      av[ct] = *(const short8*)&v_t[frow * 256 + (((c * 4 + lq) ^ (frow & 7)) << 3)];
    }
#pragma unroll
    for (int qi = 0; qi < 4; ++qi) {
      short8 bw = *(const short8*)&wsl[qi * 16 + lr][lq * 4];
      acc_den[qi] = __builtin_amdgcn_mfma_f32_16x16x32_bf16(ones, bw, acc_den[qi], 0, 0, 0);
#pragma unroll
      for (int ct = 0; ct < 4; ++ct)
        acc_pv[qi][ct] = __builtin_amdgcn_mfma_f32_16x16x32_bf16(av[ct], bw, acc_pv[qi][ct], 0, 0, 0);
    }

#pragma unroll
    for (int j = 0; j < 2; ++j)
#pragma unroll
      for (int kk = 0; kk < 2; ++kk)
        bkc[j][kk] = bkn[j][kk];
  }

#pragma unroll
  for (int qi = 0; qi < 4; ++qi) {
    float inv = 1.0f / (acc_den[qi][0] + 1e-10f);
    long orow = (qrow0 + qi * 16 + lr) * 1024 + hc;
#pragma unroll
    for (int ct = 0; ct < 4; ++ct) {
      ushort4v p;
#pragma unroll
      for (int r = 0; r < 4; ++r) p[r] = f2bf(acc_pv[qi][ct][r] * inv);
      *(ushort4v*)&attout[orow + ct * 16 + lq * 4] = p;
    }
  }
}

extern "C" void kernel_launch(void* const* d_in, const int* in_sizes, int n_in,
                              void* d_out, int out_size, void* d_ws, size_t ws_size,
                              hipStream_t stream) {
  (void)in_sizes; (void)n_in; (void)out_size; (void)ws_size;
  const float* x    = (const float*)d_in[0];
  const float* Wqkv = (const float*)d_in[1];
  const float* Wout = (const float*)d_in[2];
  float* out = (float*)d_out;
  char* ws = (char*)d_ws;

  // workspace layout (80 MB). xb aliases attout: xb is dead before attn writes.
  unsigned short* xb     = (unsigned short*)(ws);               // 33,554,432 B
  unsigned short* attout = (unsigned short*)(ws);               // (same region)
  unsigned short* wqkvb  = (unsigned short*)(ws + 33554432);    //  6,291,456 B
  unsigned short* woutb  = (unsigned short*)(ws + 39845888);    //  2,097,152 B
  unsigned short* qbuf   = (unsigned short*)(ws + 41943040);    // 33,554,432 B
  unsigned short* kbuf   = (unsigned short*)(ws + 75497472);    //  4,194,304 B
  unsigned short* vtb    = (unsigned short*)(ws + 79691776);    //  4,194,304 B

  cvt_kernel<<<16384, 256, 0, stream>>>(x, xb, 16777216);
  cvt_kernel<<<3072, 256, 0, stream>>>(Wqkv, wqkvb, 3 * 1024 * 1024);
  cvt_kernel<<<1024, 256, 0, stream>>>(Wout, woutb, 1024 * 1024);

  // Q = (x @ Wq^T) * hd^-0.5  -> qbuf [16384][1024] bf16  (8-phase 256^2)
  gemm8p<false><<<dim3(64, 4), 512, 0, stream>>>(xb, wqkvb, (void*)qbuf, 0.125f);
  // K,V at dilated rows (every 8th): K -> kbuf [2048][1024], V -> vtb (sigma V^T)
  gemm_bt<2><<<dim3(16, 16), 256, 0, stream>>>(
      xb, wqkvb + 1024 * 1024, (void*)kbuf, vtb, 1.0f, 8192, 1024, 1024);

  attn_kernel<<<1024, 256, 0, stream>>>(qbuf, kbuf, vtb, attout);

  // final projection: out = attout @ Wout^T (f32 output, 8-phase 256^2)
  gemm8p<true><<<dim3(64, 4), 512, 0, stream>>>(attout, woutb, (void*)out, 1.0f);
}